// Round 8
// baseline (4027.769 us; speedup 1.0000x reference)
//
#include <hip/hip_runtime.h>
#include <hip/hip_bf16.h>
#include <cstdint>
#include <cstddef>

#define NEc 16
#define SSc 16
#define BBc 256
#define INc 61
#define HHc 1024
#define LLc 512
#define H3c 3072
#define NEBc 4096   // NE*B
#define KXc 64      // x width padded 61->64
#define HB  16      // h-blocks of 64

typedef __hip_bfloat16 bf16;
typedef __attribute__((ext_vector_type(8))) short bf16x8;   // 8 bf16 = 4 VGPR (MFMA A/B frag)
typedef __attribute__((ext_vector_type(4))) float f32x4;    // MFMA C/D frag
typedef __attribute__((ext_vector_type(4))) short s16x4;    // 4 bf16 packed store

__device__ __forceinline__ void gload16(const void* g, void* l){
    __builtin_amdgcn_global_load_lds((const __attribute__((address_space(1))) unsigned int*)g,
                                     (__attribute__((address_space(3))) unsigned int*)l, 16, 0, 0);
}

__device__ __forceinline__ float sigmoidf_(float x){ return 1.0f/(1.0f+__expf(-x)); }

// One work-slice for the multi-role fused kernel.
// mode: -1 = inactive, 0 = fused GRU cell, 1 = output-projection+softmax.
// GRU: pre-act = A0@Wlo[0:K0] + A1@Wlo[K0:K0+K1] + A2@Whi (r,z always; 'in'
// from the lo phases, 'hn' from the hi phase), then full gate math in-register.
// ALL buffers per dispatch are read-only or write-only (fp32 h double-buffered:
// read hin, write hout) -> no RMW, no intra-dispatch W/R pairs across z-planes.
// OWSM: A0 = h bf16, Wlo = o_w padded [64][1024], bp = o_b, hout = out, K0 = t.
struct Slice {
    const bf16* A0; int lda0; int K0;
    const bf16* A1; int lda1; int K1;
    const bf16* A2; int lda2;
    const bf16* Wlo;
    const bf16* Whi;
    const float* bp;
    const float* hin;
    float* hout;
    bf16* hbout;
    bf16* out2;
    int mode;
};

// ---------------------------------------------------------------------------
// Fused GRU body. Packed weight layout per hb (64 h-cols): 192 B-rows,
// row c: g=c>>4, hsub=g/3, gate=g%3 (r,z,n), h-col = hb*64+hsub*16+(c&15).
// Wave (wm,wc): wm = row half, wc = hsub pair. Each lane holds r,z,in,hn of
// one h element -> pure-register epilogue (no LDS exchange, balanced MFMAs).
// BM=128 (MR=4): 10 ds_read_b128 feed 24 wave-MFMAs per k-step.
// ---------------------------------------------------------------------------
template<int BM>
__device__ void gru_body(const Slice& s, char* smem)
{
    constexpr int MR = BM/32;
    char* sA = smem;
    char* sB = smem + BM*128;

    const int tid  = threadIdx.x;
    const int lane = tid & 63;
    const int wave = tid >> 6;
    const int wm   = wave >> 1;
    const int wc   = wave & 1;
    const int lr   = lane & 15;
    const int lk   = lane >> 4;
    const int hb   = blockIdx.x;
    const int m0   = blockIdx.y * BM;

    const int Klo = s.K0 + s.K1;
    const bf16* WloB = s.Wlo + (size_t)hb*192*Klo;
    const bf16* WhiB = s.Whi + (size_t)hb*192*1024;

    f32x4 acc[MR][2][4];                        // [mi][hsub-local][r,z,in,hn]
    #pragma unroll
    for (int mi=0;mi<MR;mi++)
      #pragma unroll
      for (int hs=0;hs<2;hs++)
        #pragma unroll
        for (int g=0;g<4;g++)
          #pragma unroll
          for (int j=0;j<4;j++) acc[mi][hs][g][j] = 0.f;

    bool first = true;

    // ---- lo phases: r,z,'in' over A0 (K0) then A1 (K1), weights Wlo ----
    for (int k0 = 0; k0 < Klo; k0 += 64){
        if (!first) __syncthreads();
        first = false;
        const bf16* Ab; int lda, ac0;
        if (k0 < s.K0){ Ab = s.A0; lda = s.lda0; ac0 = k0; }
        else          { Ab = s.A1; lda = s.lda1; ac0 = k0 - s.K0; }
        #pragma unroll
        for (int i=0;i<MR;i++){
            const int o = i*4096 + tid*16;
            const int u = o ^ (((o>>7)&7)<<4);
            gload16(Ab + (size_t)(m0 + (u>>7))*lda + ac0 + ((u&127)>>1), sA + o);
        }
        #pragma unroll
        for (int i=0;i<6;i++){
            const int o = i*4096 + tid*16;
            const int u = o ^ (((o>>7)&7)<<4);
            gload16(WloB + (size_t)(u>>7)*Klo + k0 + ((u&127)>>1), sB + o);
        }
        __syncthreads();
        #pragma unroll
        for (int ks=0;ks<2;ks++){
            bf16x8 av[MR];
            #pragma unroll
            for (int mi=0;mi<MR;mi++){
                const int r = wm*(BM/2) + mi*16 + lr;
                const int u = r*128 + ks*64 + lk*16;
                av[mi] = *(const bf16x8*)(sA + (u ^ ((r&7)<<4)));
            }
            #pragma unroll
            for (int hs=0;hs<2;hs++)
              #pragma unroll
              for (int g3=0;g3<3;g3++){
                const int br = ((wc*2+hs)*3 + g3)*16 + lr;
                const int u  = br*128 + ks*64 + lk*16;
                const bf16x8 bv = *(const bf16x8*)(sB + (u ^ ((br&7)<<4)));
                if (g3==0){
                    #pragma unroll
                    for (int mi=0;mi<MR;mi++)
                        acc[mi][hs][0] = __builtin_amdgcn_mfma_f32_16x16x32_bf16(av[mi], bv, acc[mi][hs][0], 0,0,0);
                } else if (g3==1){
                    #pragma unroll
                    for (int mi=0;mi<MR;mi++)
                        acc[mi][hs][1] = __builtin_amdgcn_mfma_f32_16x16x32_bf16(av[mi], bv, acc[mi][hs][1], 0,0,0);
                } else {
                    #pragma unroll
                    for (int mi=0;mi<MR;mi++)
                        acc[mi][hs][2] = __builtin_amdgcn_mfma_f32_16x16x32_bf16(av[mi], bv, acc[mi][hs][2], 0,0,0);
                }
              }
        }
    }

    // ---- hi phase: r,z,'hn' over A2 (K=1024), weights Whi ----
    for (int k0 = 0; k0 < 1024; k0 += 64){
        if (!first) __syncthreads();
        first = false;
        #pragma unroll
        for (int i=0;i<MR;i++){
            const int o = i*4096 + tid*16;
            const int u = o ^ (((o>>7)&7)<<4);
            gload16(s.A2 + (size_t)(m0 + (u>>7))*s.lda2 + k0 + ((u&127)>>1), sA + o);
        }
        #pragma unroll
        for (int i=0;i<6;i++){
            const int o = i*4096 + tid*16;
            const int u = o ^ (((o>>7)&7)<<4);
            gload16(WhiB + (size_t)(u>>7)*1024 + k0 + ((u&127)>>1), sB + o);
        }
        __syncthreads();
        #pragma unroll
        for (int ks=0;ks<2;ks++){
            bf16x8 av[MR];
            #pragma unroll
            for (int mi=0;mi<MR;mi++){
                const int r = wm*(BM/2) + mi*16 + lr;
                const int u = r*128 + ks*64 + lk*16;
                av[mi] = *(const bf16x8*)(sA + (u ^ ((r&7)<<4)));
            }
            #pragma unroll
            for (int hs=0;hs<2;hs++)
              #pragma unroll
              for (int g3=0;g3<3;g3++){
                const int br = ((wc*2+hs)*3 + g3)*16 + lr;
                const int u  = br*128 + ks*64 + lk*16;
                const bf16x8 bv = *(const bf16x8*)(sB + (u ^ ((br&7)<<4)));
                if (g3==0){
                    #pragma unroll
                    for (int mi=0;mi<MR;mi++)
                        acc[mi][hs][0] = __builtin_amdgcn_mfma_f32_16x16x32_bf16(av[mi], bv, acc[mi][hs][0], 0,0,0);
                } else if (g3==1){
                    #pragma unroll
                    for (int mi=0;mi<MR;mi++)
                        acc[mi][hs][1] = __builtin_amdgcn_mfma_f32_16x16x32_bf16(av[mi], bv, acc[mi][hs][1], 0,0,0);
                } else {
                    #pragma unroll
                    for (int mi=0;mi<MR;mi++)
                        acc[mi][hs][3] = __builtin_amdgcn_mfma_f32_16x16x32_bf16(av[mi], bv, acc[mi][hs][3], 0,0,0);
                }
              }
        }
    }

    // ---- pure-register epilogue (hin read-only, hout write-only) ----
    #pragma unroll
    for (int hs=0;hs<2;hs++){
        const int hsub = wc*2 + hs;
        const int hc   = hb*64 + hsub*16 + lr;
        const float bpr  = s.bp[hb*256 +       hsub*16 + lr];
        const float bpz  = s.bp[hb*256 +  64 + hsub*16 + lr];
        const float bpin = s.bp[hb*256 + 128 + hsub*16 + lr];
        const float bphn = s.bp[hb*256 + 192 + hsub*16 + lr];
        #pragma unroll
        for (int mi=0;mi<MR;mi++)
          #pragma unroll
          for (int j=0;j<4;j++){
            const int rl = wm*(BM/2) + mi*16 + lk*4 + j;   // C/D: row=(lane>>4)*4+j
            const int m  = m0 + rl;
            const float r = sigmoidf_(acc[mi][hs][0][j] + bpr);
            const float z = sigmoidf_(acc[mi][hs][1][j] + bpz);
            const float n = tanhf(acc[mi][hs][2][j] + bpin + r*(acc[mi][hs][3][j] + bphn));
            const size_t off = (size_t)m*HHc + hc;
            const float hnew = (1.f - z)*n + z*s.hin[off];
            s.hout[off] = hnew;
            const bf16 hb16 = __float2bfloat16(hnew);
            s.hbout[off] = hb16;
            if (s.out2) s.out2[off] = hb16;
          }
    }
}

// ---------------------------------------------------------------------------
// Output projection + softmax body (64-row tile per active block).
// BM=64: active iff x==0, tile = y. BM=128: active iff x<2, tile = y*2+x.
// logits = A0 @ Wlo(o_w padded)^T + bp(o_b); softmax over 61; scatter to hout.
// ---------------------------------------------------------------------------
template<int BM>
__device__ void owsm_body(const Slice& s, char* smem)
{
    int rt;
    if constexpr (BM==128){
        if (blockIdx.x >= 2) return;
        rt = blockIdx.y*2 + blockIdx.x;
    } else {
        if (blockIdx.x != 0) return;
        rt = blockIdx.y;
    }
    char* sA = smem; char* sB = smem + 8192;
    float* lg = (float*)(smem + 16384);        // [64][68]
    const int tid  = threadIdx.x;
    const int lane = tid & 63;
    const int wave = tid >> 6;
    const int wm   = wave >> 1;
    const int wc   = wave & 1;
    const int lr   = lane & 15;
    const int lk   = lane >> 4;
    const int m0   = rt * 64;
    const int t    = s.K0;

    f32x4 acc[2][2];
    #pragma unroll
    for (int mi=0;mi<2;mi++)
      #pragma unroll
      for (int ni=0;ni<2;ni++)
        #pragma unroll
        for (int j=0;j<4;j++) acc[mi][ni][j]=0.f;

    for (int k0=0;k0<1024;k0+=64){
        if (k0) __syncthreads();
        #pragma unroll
        for (int i=0;i<2;i++){
            const int o = i*4096 + tid*16;
            const int u = o ^ (((o>>7)&7)<<4);
            gload16(s.A0 + (size_t)(m0 + (u>>7))*1024 + k0 + ((u&127)>>1), sA + o);
        }
        #pragma unroll
        for (int i=0;i<2;i++){
            const int o = i*4096 + tid*16;
            const int u = o ^ (((o>>7)&7)<<4);
            gload16(s.Wlo + (size_t)(u>>7)*1024 + k0 + ((u&127)>>1), sB + o);
        }
        __syncthreads();
        #pragma unroll
        for (int ks=0;ks<2;ks++){
            bf16x8 av[2], bv[2];
            #pragma unroll
            for (int mi=0;mi<2;mi++){
                const int r = wm*32 + mi*16 + lr;
                const int u = r*128 + ks*64 + lk*16;
                av[mi] = *(const bf16x8*)(sA + (u ^ ((r&7)<<4)));
            }
            #pragma unroll
            for (int ni=0;ni<2;ni++){
                const int r = wc*32 + ni*16 + lr;
                const int u = r*128 + ks*64 + lk*16;
                bv[ni] = *(const bf16x8*)(sB + (u ^ ((r&7)<<4)));
            }
            #pragma unroll
            for (int mi=0;mi<2;mi++)
              #pragma unroll
              for (int ni=0;ni<2;ni++)
                acc[mi][ni] = __builtin_amdgcn_mfma_f32_16x16x32_bf16(av[mi], bv[ni], acc[mi][ni], 0,0,0);
        }
    }
    #pragma unroll
    for (int mi=0;mi<2;mi++)
      #pragma unroll
      for (int ni=0;ni<2;ni++)
        #pragma unroll
        for (int j=0;j<4;j++){
            const int rl = wm*32 + mi*16 + lk*4 + j;
            const int c  = wc*32 + ni*16 + lr;
            lg[rl*68 + c] = (c < INc) ? (acc[mi][ni][j] + s.bp[c]) : -1e30f;
        }
    __syncthreads();
    const int row = tid >> 2;
    const int q   = tid & 3;
    float mx = -1e30f;
    #pragma unroll
    for (int i=0;i<16;i++) mx = fmaxf(mx, lg[row*68 + q*16+i]);
    mx = fmaxf(mx, __shfl_xor(mx,1));
    mx = fmaxf(mx, __shfl_xor(mx,2));
    float ev[16];
    float sum = 0.f;
    #pragma unroll
    for (int i=0;i<16;i++){ ev[i] = __expf(lg[row*68 + q*16+i] - mx); sum += ev[i]; }
    sum += __shfl_xor(sum,1);
    sum += __shfl_xor(sum,2);
    const float inv = 1.f/sum;
    const int R = m0 + row;
    const int ne = R >> 8, b = R & 255;
    float* op = s.hout + ((size_t)((ne*SSc + t)*BBc + b))*INc;
    #pragma unroll
    for (int i=0;i<16;i++){
        const int c = q*16 + i;
        if (c < INc) op[c] = ev[i]*inv;
    }
}

// ---------------------------------------------------------------------------
// Multi-role fused step kernel: one independent Slice per blockIdx.z.
// ---------------------------------------------------------------------------
template<int BM>
__global__ __launch_bounds__(256)
void fused_step(Slice s0, Slice s1, Slice s2)
{
    constexpr int GRUSZ  = (BM+192)*128;
    constexpr int OWSZ   = 16384 + 64*68*4;
    constexpr int SMEMSZ = (BM>=64 && OWSZ > GRUSZ) ? OWSZ : GRUSZ;
    __shared__ char smem[SMEMSZ];
    const Slice& s = (blockIdx.z==0) ? s0 : (blockIdx.z==1) ? s1 : s2;
    if (s.mode < 0) return;
    if constexpr (BM>=64){
        if (s.mode == 1){ owsm_body<BM>(s, smem); return; }
    }
    gru_body<BM>(s, smem);
}

// ---------------------------------------------------------------------------
// plain bf16 GEMM-NT (proven): C[M,N] = A[M,K] @ B[N,K]^T, C fp32 (embedding)
// ---------------------------------------------------------------------------
template<int BM,int BN>
__global__ __launch_bounds__(256)
void gemm_bf(const bf16* __restrict__ A, const bf16* __restrict__ Bm, float* __restrict__ C,
             int K, int ldc)
{
    constexpr int WAVES_M = (BM==128) ? 2 : 1;
    constexpr int WM = BM / WAVES_M;
    constexpr int WN = BN / (4/WAVES_M);
    constexpr int MR = WM / 16;
    constexpr int NR = WN / 16;
    constexpr int ASW = (BM*128)/4096;
    constexpr int BSW = (BN*128)/4096;

    __shared__ char smem[(BM+BN)*128];
    char* sA = smem;
    char* sB = smem + BM*128;

    const int tid  = threadIdx.x;
    const int lane = tid & 63;
    const int wave = tid >> 6;
    const int wm   = (WAVES_M==2) ? (wave>>1) : 0;
    const int wn   = (WAVES_M==2) ? (wave&1)  : wave;
    const int lr   = lane & 15;
    const int lk   = lane >> 4;
    const int m0   = blockIdx.y * BM;
    const int n0   = blockIdx.x * BN;

    f32x4 acc[MR][NR];
    #pragma unroll
    for (int mi=0;mi<MR;mi++)
      #pragma unroll
      for (int ni=0;ni<NR;ni++)
        #pragma unroll
        for (int j=0;j<4;j++) acc[mi][ni][j] = 0.f;

    for (int k0 = 0; k0 < K; k0 += 64){
        if (k0) __syncthreads();
        #pragma unroll
        for (int i=0;i<ASW;i++){
            const int o = i*4096 + tid*16;
            const int u = o ^ (((o>>7)&7)<<4);
            gload16(A + (size_t)(m0 + (u>>7))*K + k0 + ((u&127)>>1), sA + o);
        }
        #pragma unroll
        for (int i=0;i<BSW;i++){
            const int o = i*4096 + tid*16;
            const int u = o ^ (((o>>7)&7)<<4);
            gload16(Bm + (size_t)(n0 + (u>>7))*K + k0 + ((u&127)>>1), sB + o);
        }
        __syncthreads();
        #pragma unroll
        for (int ks=0;ks<2;ks++){
            bf16x8 av[MR], bv[NR];
            #pragma unroll
            for (int mi=0;mi<MR;mi++){
                const int r = wm*WM + mi*16 + lr;
                const int u = r*128 + ks*64 + lk*16;
                av[mi] = *(const bf16x8*)(sA + (u ^ ((r&7)<<4)));
            }
            #pragma unroll
            for (int ni=0;ni<NR;ni++){
                const int r = wn*WN + ni*16 + lr;
                const int u = r*128 + ks*64 + lk*16;
                bv[ni] = *(const bf16x8*)(sB + (u ^ ((r&7)<<4)));
            }
            #pragma unroll
            for (int mi=0;mi<MR;mi++)
              #pragma unroll
              for (int ni=0;ni<NR;ni++)
                acc[mi][ni] = __builtin_amdgcn_mfma_f32_16x16x32_bf16(av[mi], bv[ni], acc[mi][ni], 0,0,0);
        }
    }
    #pragma unroll
    for (int mi=0;mi<MR;mi++)
      #pragma unroll
      for (int ni=0;ni<NR;ni++)
        #pragma unroll
        for (int j=0;j<4;j++){
            const int r = m0 + wm*WM + mi*16 + lk*4 + j;
            const int c = n0 + wn*WN + ni*16 + lr;
            C[(size_t)r*ldc + c] = acc[mi][ni][j];
        }
}

// ---------------------------------------------------------------------------
// setup kernels
// ---------------------------------------------------------------------------
__global__ __launch_bounds__(256) void pack_w2(const float* __restrict__ src, int srcld,
                                               int col0, int Kvalid, int Kchunk,
                                               bf16* __restrict__ dst, int dstld, int dstc0,
                                               int total){
    const int idx = blockIdx.x*256 + threadIdx.x;
    if (idx >= total) return;
    const int k  = idx % Kchunk;
    const int c  = (idx / Kchunk) % 192;
    const int hb = idx / (Kchunk*192);
    const int g  = c >> 4;
    const int hsub = g/3;
    const int gate = g - hsub*3;
    const int row = gate*HHc + hb*64 + hsub*16 + (c & 15);
    const float v = (k < Kvalid) ? src[(size_t)row*srcld + col0 + k] : 0.f;
    dst[((size_t)hb*192 + c)*dstld + dstc0 + k] = __float2bfloat16(v);
}

// bp[hb][256] = [bih_r+bhh_r][bih_z+bhh_z][bih_n][bhh_n], within-64 = h offset
__global__ __launch_bounds__(256) void pack_bias(const float* __restrict__ bih,
                                                 const float* __restrict__ bhh,
                                                 float* __restrict__ bp){
    const int idx = blockIdx.x*256 + threadIdx.x;
    if (idx >= HB*256) return;
    const int c  = idx & 255;
    const int hb = idx >> 8;
    const int i  = hb*64 + (c&63);
    const int g  = c >> 6;
    float v;
    if      (g==0) v = bih[i] + bhh[i];
    else if (g==1) v = bih[HHc+i] + bhh[HHc+i];
    else if (g==2) v = bih[2*HHc+i];
    else           v = bhh[2*HHc+i];
    bp[idx] = v;
}

__global__ __launch_bounds__(256) void cvt_bf16_k(const float* __restrict__ in, bf16* __restrict__ out, int n4){
    const int i = blockIdx.x*256 + threadIdx.x;
    if (i >= n4) return;
    const f32x4 v = *(const f32x4*)(in + (size_t)i*4);
    union { s16x4 s; bf16 b[4]; } u;
    #pragma unroll
    for (int j=0;j<4;j++) u.b[j] = __float2bfloat16(v[j]);
    *(s16x4*)(out + (size_t)i*4) = u.s;
}

// o_w [61][1024] -> owb [64][1024] zero-padded rows
__global__ __launch_bounds__(256) void pad_ow(const float* __restrict__ w, bf16* __restrict__ o){
    const int idx = blockIdx.x*256 + threadIdx.x;
    if (idx >= KXc*HHc) return;
    const int r = idx >> 10;
    o[idx] = __float2bfloat16(r < INc ? w[(size_t)r*HHc + (idx & (HHc-1))] : 0.f);
}

// target [NE*S][B][61] -> xb bf16 [S][NE*B][64] zero-padded
__global__ __launch_bounds__(256) void build_xb(const float* __restrict__ t, bf16* __restrict__ xb){
    const int idx = blockIdx.x*256 + threadIdx.x;
    if (idx >= SSc*NEBc*KXc) return;
    const int c  = idx & 63;
    const int rr = idx >> 6;
    const int s  = rr >> 12;
    const int r  = rr & 4095;
    const int ne = r >> 8;
    const int b  = r & 255;
    const float v = (c < INc) ? t[(((size_t)(ne*SSc + s)*BBc + b)*INc) + c] : 0.f;
    xb[idx] = __float2bfloat16(v);
}

// h0 [2][256][1024] -> h0cf/h1cf fp32 + bf16 shadows
__global__ __launch_bounds__(256) void init_hc(const float* __restrict__ h0,
                                               float* __restrict__ h0c, float* __restrict__ h1c,
                                               bf16* __restrict__ h0cb, bf16* __restrict__ h1cb){
    const int i = blockIdx.x*256 + threadIdx.x;
    if (i >= (BBc*HHc)/4) return;
    const int e = i*4;
    f32x4 a = *(const f32x4*)(h0 + e);
    f32x4 b = *(const f32x4*)(h0 + BBc*HHc + e);
    union { s16x4 v; bf16 q[4]; } ua, ub;
    #pragma unroll
    for (int j=0;j<4;j++){ ua.q[j]=__float2bfloat16(a[j]); ub.q[j]=__float2bfloat16(b[j]); }
    *(f32x4*)(h0c + e) = a; *(f32x4*)(h1c + e) = b;
    *(s16x4*)(h0cb + e) = ua.v; *(s16x4*)(h1cb + e) = ub.v;
}

// h0_dec [NE][2][256][1024] -> hd0f/hd1f [NE*B][H] fp32 + bf16
__global__ __launch_bounds__(256) void init_hd(const float* __restrict__ hd,
                                               float* __restrict__ hd0, float* __restrict__ hd1,
                                               bf16* __restrict__ hd0b, bf16* __restrict__ hd1b){
    const int i = blockIdx.x*256 + threadIdx.x;
    if (i >= (NEBc*HHc)/4) return;
    const int e  = i*4;
    const int hh = e & (HHc-1);
    const int r  = e >> 10;
    const int ne = r >> 8;
    const int b  = r & 255;
    f32x4 a = *(const f32x4*)(hd + (((size_t)ne*2 + 0)*BBc + b)*HHc + hh);
    f32x4 c = *(const f32x4*)(hd + (((size_t)ne*2 + 1)*BBc + b)*HHc + hh);
    union { s16x4 v; bf16 q[4]; } ua, uc;
    #pragma unroll
    for (int j=0;j<4;j++){ ua.q[j]=__float2bfloat16(a[j]); uc.q[j]=__float2bfloat16(c[j]); }
    *(f32x4*)(hd0 + e) = a; *(f32x4*)(hd1 + e) = c;
    *(s16x4*)(hd0b + e) = ua.v; *(s16x4*)(hd1b + e) = uc.v;
}

__global__ __launch_bounds__(256) void bias_tanh4(const float* __restrict__ in,
                                                  const float* __restrict__ b, bf16* __restrict__ out){
    const int i = blockIdx.x*256 + threadIdx.x;
    if (i >= (NEBc*LLc)/4) return;
    const int e = i*4;
    const int c = e & (LLc-1);
    f32x4 v = *(const f32x4*)(in + e);
    f32x4 bb = *(const f32x4*)(b + c);
    union { s16x4 s; bf16 q[4]; } u;
    #pragma unroll
    for (int j=0;j<4;j++) u.q[j] = __float2bfloat16(tanhf(v[j] + bb[j]));
    *(s16x4*)(out + e) = u.s;
}

// ---------------- host side ----------------

extern "C" void kernel_launch(void* const* d_in, const int* in_sizes, int n_in,
                              void* d_out, int out_size, void* d_ws, size_t ws_size,
                              hipStream_t stream)
{
    const float* target = (const float*)d_in[0];
    const float* latent = (const float*)d_in[1];
    const float* h0     = (const float*)d_in[2];
    const float* h0_dec = (const float*)d_in[3];
    const float* c_wih0 = (const float*)d_in[4];
    const float* c_whh0 = (const float*)d_in[5];
    const float* c_bih0 = (const float*)d_in[6];
    const float* c_bhh0 = (const float*)d_in[7];
    const float* c_wih1 = (const float*)d_in[8];
    const float* c_whh1 = (const float*)d_in[9];
    const float* c_bih1 = (const float*)d_in[10];
    const float* c_bhh1 = (const float*)d_in[11];
    const float* ce_w   = (const float*)d_in[12];
    const float* ce_b   = (const float*)d_in[13];
    const float* d_wih0 = (const float*)d_in[14];
    const float* d_whh0 = (const float*)d_in[15];
    const float* d_bih0 = (const float*)d_in[16];
    const float* d_bhh0 = (const float*)d_in[17];
    const float* d_wih1 = (const float*)d_in[18];
    const float* d_whh1 = (const float*)d_in[19];
    const float* d_bih1 = (const float*)d_in[20];
    const float* d_bhh1 = (const float*)d_in[21];
    const float* o_w    = (const float*)d_in[22];
    const float* o_b    = (const float*)d_in[23];
    float* out = (float*)d_out;

    // ---- workspace (fp32 h fully double-buffered: no RMW anywhere) ----
    float* fp = (float*)d_ws;
    auto fa = [&](size_t n){ float* q = fp; fp += n; return q; };
    float* hd0f[2] = { fa((size_t)NEBc*HHc), fa((size_t)NEBc*HHc) };
    float* hd1f[2] = { fa((size_t)NEBc*HHc), fa((size_t)NEBc*HHc) };
    float* h0cf[2] = { fa((size_t)BBc*HHc),  fa((size_t)BBc*HHc) };
    float* h1cf[2] = { fa((size_t)BBc*HHc),  fa((size_t)BBc*HHc) };
    float* emb   = fa((size_t)NEBc*LLc);
    float* bp_c0 = fa(HB*256);
    float* bp_c1 = fa(HB*256);
    float* bp_d0 = fa(HB*256);
    float* bp_d1 = fa(HB*256);

    bf16* bbp = (bf16*)fp;
    auto ba = [&](size_t n){ bf16* q = bbp; bbp += n; return q; };
    bf16* hd0b[2] = { ba((size_t)NEBc*HHc), ba((size_t)NEBc*HHc) };
    bf16* hd1b[2] = { ba((size_t)NEBc*HHc), ba((size_t)NEBc*HHc) };
    bf16* h0cb[2] = { ba((size_t)BBc*HHc),  ba((size_t)BBc*HHc) };
    bf16* h1cb[2] = { ba((size_t)BBc*HHc),  ba((size_t)BBc*HHc) };
    bf16* xb     = ba((size_t)SSc*NEBc*KXc);
    bf16* coutb  = ba((size_t)NEBc*HHc);
    bf16* embb   = ba((size_t)NEBc*LLc);
    bf16* latb   = ba((size_t)BBc*LLc);
    bf16* Wloc0  = ba((size_t)HB*192*LLc);      // conductor l0: latent phase (K=512)
    bf16* Whic0  = ba((size_t)HB*192*HHc);
    bf16* Wloc1  = ba((size_t)HB*192*HHc);
    bf16* Whic1  = ba((size_t)HB*192*HHc);
    bf16* Wlod0f = ba((size_t)HB*192*576);      // decoder l0: [x(64) | emb(512)]
    bf16* Whid0  = ba((size_t)HB*192*HHc);
    bf16* Wlod1  = ba((size_t)HB*192*HHc);
    bf16* Whid1  = ba((size_t)HB*192*HHc);
    bf16* cewb   = ba((size_t)LLc*HHc);
    bf16* owb    = ba((size_t)KXc*HHc);

    auto packw = [&](const float* src, int srcld, int col0, int kv, int kchunk,
                     bf16* dst, int dstld, int dstc0){
        const int tot = HB*192*kchunk;
        hipLaunchKernelGGL(pack_w2, dim3((tot+255)/256), dim3(256),0,stream,
                           src,srcld,col0,kv,kchunk,dst,dstld,dstc0,tot);
    };

    // ---- setup ----
    hipLaunchKernelGGL(cvt_bf16_k, dim3((BBc*LLc/4+255)/256), dim3(256),0,stream, latent, latb, BBc*LLc/4);
    hipLaunchKernelGGL(cvt_bf16_k, dim3((LLc*HHc/4+255)/256), dim3(256),0,stream, ce_w, cewb, LLc*HHc/4);
    hipLaunchKernelGGL(pad_ow, dim3((KXc*HHc)/256), dim3(256),0,stream, o_w, owb);
    hipLaunchKernelGGL(build_xb, dim3((SSc*NEBc*KXc)/256), dim3(256),0,stream, target, xb);
    hipLaunchKernelGGL(init_hc, dim3((BBc*HHc/4)/256), dim3(256),0,stream, h0, h0cf[0], h1cf[0], h0cb[0], h1cb[0]);
    hipLaunchKernelGGL(init_hd, dim3((NEBc*HHc/4)/256), dim3(256),0,stream, h0_dec, hd0f[0], hd1f[0], hd0b[0], hd1b[0]);
    packw(c_wih0, LLc,     0,   LLc, LLc,  Wloc0, LLc, 0);
    packw(c_whh0, HHc,     0,   HHc, HHc,  Whic0, HHc, 0);
    packw(c_wih1, HHc,     0,   HHc, HHc,  Wloc1, HHc, 0);
    packw(c_whh1, HHc,     0,   HHc, HHc,  Whic1, HHc, 0);
    packw(d_wih0, INc+LLc, 0,   INc, KXc,  Wlod0f, 576, 0);
    packw(d_wih0, INc+LLc, INc, LLc, LLc,  Wlod0f, 576, KXc);
    packw(d_whh0, HHc,     0,   HHc, HHc,  Whid0, HHc, 0);
    packw(d_wih1, HHc,     0,   HHc, HHc,  Wlod1, HHc, 0);
    packw(d_whh1, HHc,     0,   HHc, HHc,  Whid1, HHc, 0);
    hipLaunchKernelGGL(pack_bias, dim3((HB*256+255)/256), dim3(256),0,stream, c_bih0, c_bhh0, bp_c0);
    hipLaunchKernelGGL(pack_bias, dim3((HB*256+255)/256), dim3(256),0,stream, c_bih1, c_bhh1, bp_c1);
    hipLaunchKernelGGL(pack_bias, dim3((HB*256+255)/256), dim3(256),0,stream, d_bih0, d_bhh0, bp_d0);
    hipLaunchKernelGGL(pack_bias, dim3((HB*256+255)/256), dim3(256),0,stream, d_bih1, d_bhh1, bp_d1);

    // ---- slice builders (host) ----
    auto CL0 = [&](int s){ Slice x{}; x.mode=0;
        x.A0=latb; x.lda0=LLc; x.K0=LLc; x.A1=nullptr; x.lda1=0; x.K1=0;
        x.A2=h0cb[s&1]; x.lda2=HHc; x.Wlo=Wloc0; x.Whi=Whic0; x.bp=bp_c0;
        x.hin=h0cf[s&1]; x.hout=h0cf[(s+1)&1]; x.hbout=h0cb[(s+1)&1]; x.out2=nullptr; return x; };
    auto CL1 = [&](int s){ Slice x{}; x.mode=0;
        x.A0=h0cb[(s+1)&1]; x.lda0=HHc; x.K0=HHc; x.A1=nullptr; x.lda1=0; x.K1=0;
        x.A2=h1cb[s&1]; x.lda2=HHc; x.Wlo=Wloc1; x.Whi=Whic1; x.bp=bp_c1;
        x.hin=h1cf[s&1]; x.hout=h1cf[(s+1)&1]; x.hbout=h1cb[(s+1)&1];
        x.out2=coutb + (size_t)s*BBc*HHc; return x; };
    auto DL0 = [&](int t){ Slice x{}; x.mode=0;
        x.A0=xb + (size_t)t*NEBc*KXc; x.lda0=KXc; x.K0=KXc;
        x.A1=embb; x.lda1=LLc; x.K1=LLc;
        x.A2=hd0b[t&1]; x.lda2=HHc; x.Wlo=Wlod0f; x.Whi=Whid0; x.bp=bp_d0;
        x.hin=hd0f[t&1]; x.hout=hd0f[(t+1)&1]; x.hbout=hd0b[(t+1)&1]; x.out2=nullptr; return x; };
    auto DL1 = [&](int t){ Slice x{}; x.mode=0;
        x.A0=hd0b[(t+1)&1]; x.lda0=HHc; x.K0=HHc; x.A1=nullptr; x.lda1=0; x.K1=0;
        x.A2=hd1b[t&1]; x.lda2=HHc; x.Wlo=Wlod1; x.Whi=Whid1; x.bp=bp_d1;
        x.hin=hd1f[t&1]; x.hout=hd1f[(t+1)&1]; x.hbout=hd1b[(t+1)&1]; x.out2=nullptr; return x; };
    auto OW = [&](int t){ Slice x{}; x.mode=1;
        x.A0=hd1b[(t+1)&1]; x.K0=t; x.Wlo=owb; x.bp=o_b; x.hout=out; return x; };
    Slice NS{}; NS.mode = -1;

    // ---- conductor: C_init + 16 combined steps ----
    hipLaunchKernelGGL((fused_step<32>), dim3(HB, BBc/32, 1), dim3(256),0,stream, CL0(0), NS, NS);
    for (int s=0;s<NEc;s++){
        if (s < NEc-1)
            hipLaunchKernelGGL((fused_step<32>), dim3(HB, BBc/32, 2), dim3(256),0,stream,
                               CL1(s), CL0(s+1), NS);
        else
            hipLaunchKernelGGL((fused_step<32>), dim3(HB, BBc/32, 1), dim3(256),0,stream,
                               CL1(s), NS, NS);
    }

    // ---- embedding: emb = tanh(cout @ ce_w^T + b) -> bf16 ----
    hipLaunchKernelGGL((gemm_bf<64,128>), dim3(LLc/128, NEBc/64), dim3(256),0,stream,
                       coutb, cewb, emb, HHc, LLc);
    hipLaunchKernelGGL(bias_tanh4, dim3((NEBc*LLc/4)/256), dim3(256),0,stream, emb, ce_b, embb);

    // ---- decoder: D_init + 16 combined steps (BM=128) + final softmax ----
    hipLaunchKernelGGL((fused_step<128>), dim3(HB, NEBc/128, 1), dim3(256),0,stream, DL0(0), NS, NS);
    for (int t=0;t<SSc;t++){
        Slice s1 = (t < SSc-1) ? DL0(t+1) : NS;
        Slice s2 = (t >= 1) ? OW(t-1) : NS;
        const int nz = (t >= 1) ? 3 : 2;
        hipLaunchKernelGGL((fused_step<128>), dim3(HB, NEBc/128, nz), dim3(256),0,stream,
                           DL1(t), s1, s2);
    }
    hipLaunchKernelGGL((fused_step<64>), dim3(1, NEBc/64, 1), dim3(256),0,stream, OW(SSc-1), NS, NS);
}

// Round 9
// 4013.066 us; speedup vs baseline: 1.0037x; 1.0037x over previous
//
#include <hip/hip_runtime.h>
#include <hip/hip_bf16.h>
#include <cstdint>
#include <cstddef>

#define NEc 16
#define SSc 16
#define BBc 256
#define INc 61
#define HHc 1024
#define LLc 512
#define H3c 3072
#define NEBc 4096   // NE*B
#define KXc 64      // x width padded 61->64
#define HB  16      // h-blocks of 64

typedef __hip_bfloat16 bf16;
typedef __attribute__((ext_vector_type(8))) short bf16x8;   // 8 bf16 = 4 VGPR (MFMA A/B frag)
typedef __attribute__((ext_vector_type(4))) float f32x4;    // MFMA C/D frag
typedef __attribute__((ext_vector_type(4))) short s16x4;    // 4 bf16 packed store

__device__ __forceinline__ void gload16(const void* g, void* l){
    __builtin_amdgcn_global_load_lds((const __attribute__((address_space(1))) unsigned int*)g,
                                     (__attribute__((address_space(3))) unsigned int*)l, 16, 0, 0);
}

__device__ __forceinline__ float sigmoidf_(float x){ return 1.0f/(1.0f+__expf(-x)); }

// One work-slice for the multi-role fused kernel.
// mode: -1 = inactive, 0 = fused GRU cell, 1 = output-projection+softmax.
// GRU: pre-act = A0@Wlo[0:K0] + A1@Wlo[K0:K0+K1] + A2@Whi (r,z always; 'in'
// from the lo phases, 'hn' from the hi phase), then full gate math in-register.
// ALL buffers per dispatch are read-only or write-only (fp32 h double-buffered).
// OWSM: A0 = h bf16, Wlo = o_w padded [64][1024], bp = o_b, hout = out, K0 = t.
struct Slice {
    const bf16* A0; int lda0; int K0;
    const bf16* A1; int lda1; int K1;
    const bf16* A2; int lda2;
    const bf16* Wlo;
    const bf16* Whi;
    const float* bp;
    const float* hin;
    float* hout;
    bf16* hbout;
    bf16* out2;
    int mode;
};

// One staged k-step: stage A-tile (BM rows x 128B) + B-tile (192 rows x 128B),
// then 2 ks-halves x {r,z,NIDX} MFMAs. NIDX=2 (lo: 'in') or 3 (hi: 'hn').
// Dedicated-source macro keeps codegen register-lean (R4-proven at MR=4).
#define GRU_KSTEP(APTR, ALDA, ACOL, BPTR, BLDB, BCOL, NIDX)                              \
  {                                                                                      \
    if (!first) __syncthreads();                                                         \
    first = false;                                                                       \
    _Pragma("unroll")                                                                    \
    for (int i=0;i<MR;i++){                                                              \
        const int o = i*4096 + tid*16;                                                   \
        const int u = o ^ (((o>>7)&7)<<4);                                               \
        gload16((APTR) + (size_t)(m0 + (u>>7))*(ALDA) + (ACOL) + ((u&127)>>1), sA + o);  \
    }                                                                                    \
    _Pragma("unroll")                                                                    \
    for (int i=0;i<6;i++){                                                               \
        const int o = i*4096 + tid*16;                                                   \
        const int u = o ^ (((o>>7)&7)<<4);                                               \
        gload16((BPTR) + (size_t)(u>>7)*(BLDB) + (BCOL) + ((u&127)>>1), sB + o);         \
    }                                                                                    \
    __syncthreads();                                                                     \
    _Pragma("unroll")                                                                    \
    for (int ks=0;ks<2;ks++){                                                            \
        bf16x8 av[MR];                                                                   \
        _Pragma("unroll")                                                                \
        for (int mi=0;mi<MR;mi++){                                                       \
            const int r = wm*(BM/2) + mi*16 + lr;                                        \
            const int u = r*128 + ks*64 + lk*16;                                         \
            av[mi] = *(const bf16x8*)(sA + (u ^ ((r&7)<<4)));                            \
        }                                                                                \
        _Pragma("unroll")                                                                \
        for (int hs=0;hs<2;hs++){                                                        \
            _Pragma("unroll")                                                            \
            for (int g3=0;g3<3;g3++){                                                    \
                const int br = ((wc*2+hs)*3 + g3)*16 + lr;                               \
                const int u  = br*128 + ks*64 + lk*16;                                   \
                const bf16x8 bv = *(const bf16x8*)(sB + (u ^ ((br&7)<<4)));              \
                const int gi_ = (g3<2) ? g3 : (NIDX);                                    \
                _Pragma("unroll")                                                        \
                for (int mi=0;mi<MR;mi++)                                                \
                    acc[mi][hs][gi_] = __builtin_amdgcn_mfma_f32_16x16x32_bf16(          \
                        av[mi], bv, acc[mi][hs][gi_], 0,0,0);                            \
            }                                                                            \
        }                                                                                \
    }                                                                                    \
  }

// ---------------------------------------------------------------------------
// Fused GRU body. Packed weight layout per hb (64 h-cols): 192 B-rows,
// row c: g=c>>4, hsub=g/3, gate=g%3 (r,z,n), h-col = hb*64+hsub*16+(c&15).
// Wave (wm,wc): wm = row half, wc = hsub pair. Each lane holds r,z,in,hn of
// one h element -> pure-register epilogue. Three dedicated k-loops (A0,A1,A2)
// with compile-time-fixed sources -> register-lean at MR=4 (no R8 spills).
// ---------------------------------------------------------------------------
template<int BM>
__device__ void gru_body(const Slice& s, char* smem)
{
    constexpr int MR = BM/32;
    char* sA = smem;
    char* sB = smem + BM*128;

    const int tid  = threadIdx.x;
    const int lane = tid & 63;
    const int wave = tid >> 6;
    const int wm   = wave >> 1;
    const int wc   = wave & 1;
    const int lr   = lane & 15;
    const int lk   = lane >> 4;
    const int hb   = blockIdx.x;
    const int m0   = blockIdx.y * BM;

    const int Klo = s.K0 + s.K1;
    const bf16* WloB = s.Wlo + (size_t)hb*192*Klo;
    const bf16* WhiB = s.Whi + (size_t)hb*192*1024;

    f32x4 acc[MR][2][4];                        // [mi][hsub-local][r,z,in,hn]
    #pragma unroll
    for (int mi=0;mi<MR;mi++)
      #pragma unroll
      for (int hs=0;hs<2;hs++)
        #pragma unroll
        for (int g=0;g<4;g++)
          #pragma unroll
          for (int j=0;j<4;j++) acc[mi][hs][g][j] = 0.f;

    bool first = true;

    {   // ---- loop A: A0 x Wlo[0:K0] -> r,z,'in' ----
        const bf16* Ap = s.A0; const int Al = s.lda0; const int Kp = s.K0;
        for (int k0 = 0; k0 < Kp; k0 += 64) GRU_KSTEP(Ap, Al, k0, WloB, Klo, k0, 2)
    }
    if (s.K1 > 0){  // ---- loop B: A1 x Wlo[K0:K0+K1] -> r,z,'in' ----
        const bf16* Ap = s.A1; const int Al = s.lda1; const int Kp = s.K1; const int c0 = s.K0;
        for (int k0 = 0; k0 < Kp; k0 += 64) GRU_KSTEP(Ap, Al, k0, WloB, Klo, c0 + k0, 2)
    }
    {   // ---- loop C: A2 x Whi (K=1024) -> r,z,'hn' ----
        const bf16* Ap = s.A2; const int Al = s.lda2;
        for (int k0 = 0; k0 < 1024; k0 += 64) GRU_KSTEP(Ap, Al, k0, WhiB, 1024, k0, 3)
    }

    // ---- pure-register epilogue (hin read-only, hout write-only) ----
    #pragma unroll
    for (int hs=0;hs<2;hs++){
        const int hsub = wc*2 + hs;
        const int hc   = hb*64 + hsub*16 + lr;
        const float bpr  = s.bp[hb*256 +       hsub*16 + lr];
        const float bpz  = s.bp[hb*256 +  64 + hsub*16 + lr];
        const float bpin = s.bp[hb*256 + 128 + hsub*16 + lr];
        const float bphn = s.bp[hb*256 + 192 + hsub*16 + lr];
        #pragma unroll
        for (int mi=0;mi<MR;mi++)
          #pragma unroll
          for (int j=0;j<4;j++){
            const int rl = wm*(BM/2) + mi*16 + lk*4 + j;   // C/D: row=(lane>>4)*4+j
            const int m  = m0 + rl;
            const float r = sigmoidf_(acc[mi][hs][0][j] + bpr);
            const float z = sigmoidf_(acc[mi][hs][1][j] + bpz);
            const float n = tanhf(acc[mi][hs][2][j] + bpin + r*(acc[mi][hs][3][j] + bphn));
            const size_t off = (size_t)m*HHc + hc;
            const float hnew = (1.f - z)*n + z*s.hin[off];
            s.hout[off] = hnew;
            const bf16 hb16 = __float2bfloat16(hnew);
            s.hbout[off] = hb16;
            if (s.out2) s.out2[off] = hb16;
          }
    }
}

// ---------------------------------------------------------------------------
// Output projection + softmax body (64-row tile per active block).
// BM=64: active iff x==0, tile = y. BM=128: active iff x<2, tile = y*2+x.
// logits = A0 @ Wlo(o_w padded)^T + bp(o_b); softmax over 61; scatter to hout.
// ---------------------------------------------------------------------------
template<int BM>
__device__ void owsm_body(const Slice& s, char* smem)
{
    int rt;
    if constexpr (BM==128){
        if (blockIdx.x >= 2) return;
        rt = blockIdx.y*2 + blockIdx.x;
    } else {
        if (blockIdx.x != 0) return;
        rt = blockIdx.y;
    }
    char* sA = smem; char* sB = smem + 8192;
    float* lg = (float*)(smem + 16384);        // [64][68]
    const int tid  = threadIdx.x;
    const int lane = tid & 63;
    const int wave = tid >> 6;
    const int wm   = wave >> 1;
    const int wc   = wave & 1;
    const int lr   = lane & 15;
    const int lk   = lane >> 4;
    const int m0   = rt * 64;
    const int t    = s.K0;

    f32x4 acc[2][2];
    #pragma unroll
    for (int mi=0;mi<2;mi++)
      #pragma unroll
      for (int ni=0;ni<2;ni++)
        #pragma unroll
        for (int j=0;j<4;j++) acc[mi][ni][j]=0.f;

    for (int k0=0;k0<1024;k0+=64){
        if (k0) __syncthreads();
        #pragma unroll
        for (int i=0;i<2;i++){
            const int o = i*4096 + tid*16;
            const int u = o ^ (((o>>7)&7)<<4);
            gload16(s.A0 + (size_t)(m0 + (u>>7))*1024 + k0 + ((u&127)>>1), sA + o);
        }
        #pragma unroll
        for (int i=0;i<2;i++){
            const int o = i*4096 + tid*16;
            const int u = o ^ (((o>>7)&7)<<4);
            gload16(s.Wlo + (size_t)(u>>7)*1024 + k0 + ((u&127)>>1), sB + o);
        }
        __syncthreads();
        #pragma unroll
        for (int ks=0;ks<2;ks++){
            bf16x8 av[2], bv[2];
            #pragma unroll
            for (int mi=0;mi<2;mi++){
                const int r = wm*32 + mi*16 + lr;
                const int u = r*128 + ks*64 + lk*16;
                av[mi] = *(const bf16x8*)(sA + (u ^ ((r&7)<<4)));
            }
            #pragma unroll
            for (int ni=0;ni<2;ni++){
                const int r = wc*32 + ni*16 + lr;
                const int u = r*128 + ks*64 + lk*16;
                bv[ni] = *(const bf16x8*)(sB + (u ^ ((r&7)<<4)));
            }
            #pragma unroll
            for (int mi=0;mi<2;mi++)
              #pragma unroll
              for (int ni=0;ni<2;ni++)
                acc[mi][ni] = __builtin_amdgcn_mfma_f32_16x16x32_bf16(av[mi], bv[ni], acc[mi][ni], 0,0,0);
        }
    }
    #pragma unroll
    for (int mi=0;mi<2;mi++)
      #pragma unroll
      for (int ni=0;ni<2;ni++)
        #pragma unroll
        for (int j=0;j<4;j++){
            const int rl = wm*32 + mi*16 + lk*4 + j;
            const int c  = wc*32 + ni*16 + lr;
            lg[rl*68 + c] = (c < INc) ? (acc[mi][ni][j] + s.bp[c]) : -1e30f;
        }
    __syncthreads();
    const int row = tid >> 2;
    const int q   = tid & 3;
    float mx = -1e30f;
    #pragma unroll
    for (int i=0;i<16;i++) mx = fmaxf(mx, lg[row*68 + q*16+i]);
    mx = fmaxf(mx, __shfl_xor(mx,1));
    mx = fmaxf(mx, __shfl_xor(mx,2));
    float ev[16];
    float sum = 0.f;
    #pragma unroll
    for (int i=0;i<16;i++){ ev[i] = __expf(lg[row*68 + q*16+i] - mx); sum += ev[i]; }
    sum += __shfl_xor(sum,1);
    sum += __shfl_xor(sum,2);
    const float inv = 1.f/sum;
    const int R = m0 + row;
    const int ne = R >> 8, b = R & 255;
    float* op = s.hout + ((size_t)((ne*SSc + t)*BBc + b))*INc;
    #pragma unroll
    for (int i=0;i<16;i++){
        const int c = q*16 + i;
        if (c < INc) op[c] = ev[i]*inv;
    }
}

// ---------------------------------------------------------------------------
// Multi-role fused step kernel: one independent Slice per blockIdx.z.
// ---------------------------------------------------------------------------
template<int BM>
__global__ __launch_bounds__(256)
void fused_step(Slice s0, Slice s1, Slice s2)
{
    constexpr int GRUSZ  = (BM+192)*128;
    constexpr int OWSZ   = 16384 + 64*68*4;
    constexpr int SMEMSZ = (BM>=64 && OWSZ > GRUSZ) ? OWSZ : GRUSZ;
    __shared__ char smem[SMEMSZ];
    const Slice& s = (blockIdx.z==0) ? s0 : (blockIdx.z==1) ? s1 : s2;
    if (s.mode < 0) return;
    if constexpr (BM>=64){
        if (s.mode == 1){ owsm_body<BM>(s, smem); return; }
    }
    gru_body<BM>(s, smem);
}

// ---------------------------------------------------------------------------
// plain bf16 GEMM-NT (proven): C[M,N] = A[M,K] @ B[N,K]^T, C fp32 (embedding)
// ---------------------------------------------------------------------------
template<int BM,int BN>
__global__ __launch_bounds__(256)
void gemm_bf(const bf16* __restrict__ A, const bf16* __restrict__ Bm, float* __restrict__ C,
             int K, int ldc)
{
    constexpr int WAVES_M = (BM==128) ? 2 : 1;
    constexpr int WM = BM / WAVES_M;
    constexpr int WN = BN / (4/WAVES_M);
    constexpr int MR = WM / 16;
    constexpr int NR = WN / 16;
    constexpr int ASW = (BM*128)/4096;
    constexpr int BSW = (BN*128)/4096;

    __shared__ char smem[(BM+BN)*128];
    char* sA = smem;
    char* sB = smem + BM*128;

    const int tid  = threadIdx.x;
    const int lane = tid & 63;
    const int wave = tid >> 6;
    const int wm   = (WAVES_M==2) ? (wave>>1) : 0;
    const int wn   = (WAVES_M==2) ? (wave&1)  : wave;
    const int lr   = lane & 15;
    const int lk   = lane >> 4;
    const int m0   = blockIdx.y * BM;
    const int n0   = blockIdx.x * BN;

    f32x4 acc[MR][NR];
    #pragma unroll
    for (int mi=0;mi<MR;mi++)
      #pragma unroll
      for (int ni=0;ni<NR;ni++)
        #pragma unroll
        for (int j=0;j<4;j++) acc[mi][ni][j] = 0.f;

    for (int k0 = 0; k0 < K; k0 += 64){
        if (k0) __syncthreads();
        #pragma unroll
        for (int i=0;i<ASW;i++){
            const int o = i*4096 + tid*16;
            const int u = o ^ (((o>>7)&7)<<4);
            gload16(A + (size_t)(m0 + (u>>7))*K + k0 + ((u&127)>>1), sA + o);
        }
        #pragma unroll
        for (int i=0;i<BSW;i++){
            const int o = i*4096 + tid*16;
            const int u = o ^ (((o>>7)&7)<<4);
            gload16(Bm + (size_t)(n0 + (u>>7))*K + k0 + ((u&127)>>1), sB + o);
        }
        __syncthreads();
        #pragma unroll
        for (int ks=0;ks<2;ks++){
            bf16x8 av[MR], bv[NR];
            #pragma unroll
            for (int mi=0;mi<MR;mi++){
                const int r = wm*WM + mi*16 + lr;
                const int u = r*128 + ks*64 + lk*16;
                av[mi] = *(const bf16x8*)(sA + (u ^ ((r&7)<<4)));
            }
            #pragma unroll
            for (int ni=0;ni<NR;ni++){
                const int r = wn*WN + ni*16 + lr;
                const int u = r*128 + ks*64 + lk*16;
                bv[ni] = *(const bf16x8*)(sB + (u ^ ((r&7)<<4)));
            }
            #pragma unroll
            for (int mi=0;mi<MR;mi++)
              #pragma unroll
              for (int ni=0;ni<NR;ni++)
                acc[mi][ni] = __builtin_amdgcn_mfma_f32_16x16x32_bf16(av[mi], bv[ni], acc[mi][ni], 0,0,0);
        }
    }
    #pragma unroll
    for (int mi=0;mi<MR;mi++)
      #pragma unroll
      for (int ni=0;ni<NR;ni++)
        #pragma unroll
        for (int j=0;j<4;j++){
            const int r = m0 + wm*WM + mi*16 + lk*4 + j;
            const int c = n0 + wn*WN + ni*16 + lr;
            C[(size_t)r*ldc + c] = acc[mi][ni][j];
        }
}

// ---------------------------------------------------------------------------
// setup kernels
// ---------------------------------------------------------------------------
__global__ __launch_bounds__(256) void pack_w2(const float* __restrict__ src, int srcld,
                                               int col0, int Kvalid, int Kchunk,
                                               bf16* __restrict__ dst, int dstld, int dstc0,
                                               int total){
    const int idx = blockIdx.x*256 + threadIdx.x;
    if (idx >= total) return;
    const int k  = idx % Kchunk;
    const int c  = (idx / Kchunk) % 192;
    const int hb = idx / (Kchunk*192);
    const int g  = c >> 4;
    const int hsub = g/3;
    const int gate = g - hsub*3;
    const int row = gate*HHc + hb*64 + hsub*16 + (c & 15);
    const float v = (k < Kvalid) ? src[(size_t)row*srcld + col0 + k] : 0.f;
    dst[((size_t)hb*192 + c)*dstld + dstc0 + k] = __float2bfloat16(v);
}

// bp[hb][256] = [bih_r+bhh_r][bih_z+bhh_z][bih_n][bhh_n], within-64 = h offset
__global__ __launch_bounds__(256) void pack_bias(const float* __restrict__ bih,
                                                 const float* __restrict__ bhh,
                                                 float* __restrict__ bp){
    const int idx = blockIdx.x*256 + threadIdx.x;
    if (idx >= HB*256) return;
    const int c  = idx & 255;
    const int hb = idx >> 8;
    const int i  = hb*64 + (c&63);
    const int g  = c >> 6;
    float v;
    if      (g==0) v = bih[i] + bhh[i];
    else if (g==1) v = bih[HHc+i] + bhh[HHc+i];
    else if (g==2) v = bih[2*HHc+i];
    else           v = bhh[2*HHc+i];
    bp[idx] = v;
}

__global__ __launch_bounds__(256) void cvt_bf16_k(const float* __restrict__ in, bf16* __restrict__ out, int n4){
    const int i = blockIdx.x*256 + threadIdx.x;
    if (i >= n4) return;
    const f32x4 v = *(const f32x4*)(in + (size_t)i*4);
    union { s16x4 s; bf16 b[4]; } u;
    #pragma unroll
    for (int j=0;j<4;j++) u.b[j] = __float2bfloat16(v[j]);
    *(s16x4*)(out + (size_t)i*4) = u.s;
}

// o_w [61][1024] -> owb [64][1024] zero-padded rows
__global__ __launch_bounds__(256) void pad_ow(const float* __restrict__ w, bf16* __restrict__ o){
    const int idx = blockIdx.x*256 + threadIdx.x;
    if (idx >= KXc*HHc) return;
    const int r = idx >> 10;
    o[idx] = __float2bfloat16(r < INc ? w[(size_t)r*HHc + (idx & (HHc-1))] : 0.f);
}

// target [NE*S][B][61] -> xb bf16 [S][NE*B][64] zero-padded
__global__ __launch_bounds__(256) void build_xb(const float* __restrict__ t, bf16* __restrict__ xb){
    const int idx = blockIdx.x*256 + threadIdx.x;
    if (idx >= SSc*NEBc*KXc) return;
    const int c  = idx & 63;
    const int rr = idx >> 6;
    const int s  = rr >> 12;
    const int r  = rr & 4095;
    const int ne = r >> 8;
    const int b  = r & 255;
    const float v = (c < INc) ? t[(((size_t)(ne*SSc + s)*BBc + b)*INc) + c] : 0.f;
    xb[idx] = __float2bfloat16(v);
}

// h0 [2][256][1024] -> h0cf/h1cf fp32 + bf16 shadows
__global__ __launch_bounds__(256) void init_hc(const float* __restrict__ h0,
                                               float* __restrict__ h0c, float* __restrict__ h1c,
                                               bf16* __restrict__ h0cb, bf16* __restrict__ h1cb){
    const int i = blockIdx.x*256 + threadIdx.x;
    if (i >= (BBc*HHc)/4) return;
    const int e = i*4;
    f32x4 a = *(const f32x4*)(h0 + e);
    f32x4 b = *(const f32x4*)(h0 + BBc*HHc + e);
    union { s16x4 v; bf16 q[4]; } ua, ub;
    #pragma unroll
    for (int j=0;j<4;j++){ ua.q[j]=__float2bfloat16(a[j]); ub.q[j]=__float2bfloat16(b[j]); }
    *(f32x4*)(h0c + e) = a; *(f32x4*)(h1c + e) = b;
    *(s16x4*)(h0cb + e) = ua.v; *(s16x4*)(h1cb + e) = ub.v;
}

// h0_dec [NE][2][256][1024] -> hd0f/hd1f [NE*B][H] fp32 + bf16
__global__ __launch_bounds__(256) void init_hd(const float* __restrict__ hd,
                                               float* __restrict__ hd0, float* __restrict__ hd1,
                                               bf16* __restrict__ hd0b, bf16* __restrict__ hd1b){
    const int i = blockIdx.x*256 + threadIdx.x;
    if (i >= (NEBc*HHc)/4) return;
    const int e  = i*4;
    const int hh = e & (HHc-1);
    const int r  = e >> 10;
    const int ne = r >> 8;
    const int b  = r & 255;
    f32x4 a = *(const f32x4*)(hd + (((size_t)ne*2 + 0)*BBc + b)*HHc + hh);
    f32x4 c = *(const f32x4*)(hd + (((size_t)ne*2 + 1)*BBc + b)*HHc + hh);
    union { s16x4 v; bf16 q[4]; } ua, uc;
    #pragma unroll
    for (int j=0;j<4;j++){ ua.q[j]=__float2bfloat16(a[j]); uc.q[j]=__float2bfloat16(c[j]); }
    *(f32x4*)(hd0 + e) = a; *(f32x4*)(hd1 + e) = c;
    *(s16x4*)(hd0b + e) = ua.v; *(s16x4*)(hd1b + e) = uc.v;
}

__global__ __launch_bounds__(256) void bias_tanh4(const float* __restrict__ in,
                                                  const float* __restrict__ b, bf16* __restrict__ out){
    const int i = blockIdx.x*256 + threadIdx.x;
    if (i >= (NEBc*LLc)/4) return;
    const int e = i*4;
    const int c = e & (LLc-1);
    f32x4 v = *(const f32x4*)(in + e);
    f32x4 bb = *(const f32x4*)(b + c);
    union { s16x4 s; bf16 q[4]; } u;
    #pragma unroll
    for (int j=0;j<4;j++) u.q[j] = __float2bfloat16(tanhf(v[j] + bb[j]));
    *(s16x4*)(out + e) = u.s;
}

// ---------------- host side ----------------

extern "C" void kernel_launch(void* const* d_in, const int* in_sizes, int n_in,
                              void* d_out, int out_size, void* d_ws, size_t ws_size,
                              hipStream_t stream)
{
    const float* target = (const float*)d_in[0];
    const float* latent = (const float*)d_in[1];
    const float* h0     = (const float*)d_in[2];
    const float* h0_dec = (const float*)d_in[3];
    const float* c_wih0 = (const float*)d_in[4];
    const float* c_whh0 = (const float*)d_in[5];
    const float* c_bih0 = (const float*)d_in[6];
    const float* c_bhh0 = (const float*)d_in[7];
    const float* c_wih1 = (const float*)d_in[8];
    const float* c_whh1 = (const float*)d_in[9];
    const float* c_bih1 = (const float*)d_in[10];
    const float* c_bhh1 = (const float*)d_in[11];
    const float* ce_w   = (const float*)d_in[12];
    const float* ce_b   = (const float*)d_in[13];
    const float* d_wih0 = (const float*)d_in[14];
    const float* d_whh0 = (const float*)d_in[15];
    const float* d_bih0 = (const float*)d_in[16];
    const float* d_bhh0 = (const float*)d_in[17];
    const float* d_wih1 = (const float*)d_in[18];
    const float* d_whh1 = (const float*)d_in[19];
    const float* d_bih1 = (const float*)d_in[20];
    const float* d_bhh1 = (const float*)d_in[21];
    const float* o_w    = (const float*)d_in[22];
    const float* o_b    = (const float*)d_in[23];
    float* out = (float*)d_out;

    // ---- workspace (fp32 h fully double-buffered: no RMW anywhere) ----
    float* fp = (float*)d_ws;
    auto fa = [&](size_t n){ float* q = fp; fp += n; return q; };
    float* hd0f[2] = { fa((size_t)NEBc*HHc), fa((size_t)NEBc*HHc) };
    float* hd1f[2] = { fa((size_t)NEBc*HHc), fa((size_t)NEBc*HHc) };
    float* h0cf[2] = { fa((size_t)BBc*HHc),  fa((size_t)BBc*HHc) };
    float* h1cf[2] = { fa((size_t)BBc*HHc),  fa((size_t)BBc*HHc) };
    float* emb   = fa((size_t)NEBc*LLc);
    float* bp_c0 = fa(HB*256);
    float* bp_c1 = fa(HB*256);
    float* bp_d0 = fa(HB*256);
    float* bp_d1 = fa(HB*256);

    bf16* bbp = (bf16*)fp;
    auto ba = [&](size_t n){ bf16* q = bbp; bbp += n; return q; };
    bf16* hd0b[2] = { ba((size_t)NEBc*HHc), ba((size_t)NEBc*HHc) };
    bf16* hd1b[2] = { ba((size_t)NEBc*HHc), ba((size_t)NEBc*HHc) };
    bf16* h0cb[2] = { ba((size_t)BBc*HHc),  ba((size_t)BBc*HHc) };
    bf16* h1cb[2] = { ba((size_t)BBc*HHc),  ba((size_t)BBc*HHc) };
    bf16* xb     = ba((size_t)SSc*NEBc*KXc);
    bf16* coutb  = ba((size_t)NEBc*HHc);
    bf16* embb   = ba((size_t)NEBc*LLc);
    bf16* latb   = ba((size_t)BBc*LLc);
    bf16* Wloc0  = ba((size_t)HB*192*LLc);      // conductor l0: latent phase (K=512)
    bf16* Whic0  = ba((size_t)HB*192*HHc);
    bf16* Wloc1  = ba((size_t)HB*192*HHc);
    bf16* Whic1  = ba((size_t)HB*192*HHc);
    bf16* Wlod0f = ba((size_t)HB*192*576);      // decoder l0: [x(64) | emb(512)]
    bf16* Whid0  = ba((size_t)HB*192*HHc);
    bf16* Wlod1  = ba((size_t)HB*192*HHc);
    bf16* Whid1  = ba((size_t)HB*192*HHc);
    bf16* cewb   = ba((size_t)LLc*HHc);
    bf16* owb    = ba((size_t)KXc*HHc);

    auto packw = [&](const float* src, int srcld, int col0, int kv, int kchunk,
                     bf16* dst, int dstld, int dstc0){
        const int tot = HB*192*kchunk;
        hipLaunchKernelGGL(pack_w2, dim3((tot+255)/256), dim3(256),0,stream,
                           src,srcld,col0,kv,kchunk,dst,dstld,dstc0,tot);
    };

    // ---- setup ----
    hipLaunchKernelGGL(cvt_bf16_k, dim3((BBc*LLc/4+255)/256), dim3(256),0,stream, latent, latb, BBc*LLc/4);
    hipLaunchKernelGGL(cvt_bf16_k, dim3((LLc*HHc/4+255)/256), dim3(256),0,stream, ce_w, cewb, LLc*HHc/4);
    hipLaunchKernelGGL(pad_ow, dim3((KXc*HHc)/256), dim3(256),0,stream, o_w, owb);
    hipLaunchKernelGGL(build_xb, dim3((SSc*NEBc*KXc)/256), dim3(256),0,stream, target, xb);
    hipLaunchKernelGGL(init_hc, dim3((BBc*HHc/4)/256), dim3(256),0,stream, h0, h0cf[0], h1cf[0], h0cb[0], h1cb[0]);
    hipLaunchKernelGGL(init_hd, dim3((NEBc*HHc/4)/256), dim3(256),0,stream, h0_dec, hd0f[0], hd1f[0], hd0b[0], hd1b[0]);
    packw(c_wih0, LLc,     0,   LLc, LLc,  Wloc0, LLc, 0);
    packw(c_whh0, HHc,     0,   HHc, HHc,  Whic0, HHc, 0);
    packw(c_wih1, HHc,     0,   HHc, HHc,  Wloc1, HHc, 0);
    packw(c_whh1, HHc,     0,   HHc, HHc,  Whic1, HHc, 0);
    packw(d_wih0, INc+LLc, 0,   INc, KXc,  Wlod0f, 576, 0);
    packw(d_wih0, INc+LLc, INc, LLc, LLc,  Wlod0f, 576, KXc);
    packw(d_whh0, HHc,     0,   HHc, HHc,  Whid0, HHc, 0);
    packw(d_wih1, HHc,     0,   HHc, HHc,  Wlod1, HHc, 0);
    packw(d_whh1, HHc,     0,   HHc, HHc,  Whid1, HHc, 0);
    hipLaunchKernelGGL(pack_bias, dim3((HB*256+255)/256), dim3(256),0,stream, c_bih0, c_bhh0, bp_c0);
    hipLaunchKernelGGL(pack_bias, dim3((HB*256+255)/256), dim3(256),0,stream, c_bih1, c_bhh1, bp_c1);
    hipLaunchKernelGGL(pack_bias, dim3((HB*256+255)/256), dim3(256),0,stream, d_bih0, d_bhh0, bp_d0);
    hipLaunchKernelGGL(pack_bias, dim3((HB*256+255)/256), dim3(256),0,stream, d_bih1, d_bhh1, bp_d1);

    // ---- slice builders (host) ----
    auto CL0 = [&](int s){ Slice x{}; x.mode=0;
        x.A0=latb; x.lda0=LLc; x.K0=LLc; x.A1=nullptr; x.lda1=0; x.K1=0;
        x.A2=h0cb[s&1]; x.lda2=HHc; x.Wlo=Wloc0; x.Whi=Whic0; x.bp=bp_c0;
        x.hin=h0cf[s&1]; x.hout=h0cf[(s+1)&1]; x.hbout=h0cb[(s+1)&1]; x.out2=nullptr; return x; };
    auto CL1 = [&](int s){ Slice x{}; x.mode=0;
        x.A0=h0cb[(s+1)&1]; x.lda0=HHc; x.K0=HHc; x.A1=nullptr; x.lda1=0; x.K1=0;
        x.A2=h1cb[s&1]; x.lda2=HHc; x.Wlo=Wloc1; x.Whi=Whic1; x.bp=bp_c1;
        x.hin=h1cf[s&1]; x.hout=h1cf[(s+1)&1]; x.hbout=h1cb[(s+1)&1];
        x.out2=coutb + (size_t)s*BBc*HHc; return x; };
    auto DL0 = [&](int t){ Slice x{}; x.mode=0;
        x.A0=xb + (size_t)t*NEBc*KXc; x.lda0=KXc; x.K0=KXc;
        x.A1=embb; x.lda1=LLc; x.K1=LLc;
        x.A2=hd0b[t&1]; x.lda2=HHc; x.Wlo=Wlod0f; x.Whi=Whid0; x.bp=bp_d0;
        x.hin=hd0f[t&1]; x.hout=hd0f[(t+1)&1]; x.hbout=hd0b[(t+1)&1]; x.out2=nullptr; return x; };
    auto DL1 = [&](int t){ Slice x{}; x.mode=0;
        x.A0=hd0b[(t+1)&1]; x.lda0=HHc; x.K0=HHc; x.A1=nullptr; x.lda1=0; x.K1=0;
        x.A2=hd1b[t&1]; x.lda2=HHc; x.Wlo=Wlod1; x.Whi=Whid1; x.bp=bp_d1;
        x.hin=hd1f[t&1]; x.hout=hd1f[(t+1)&1]; x.hbout=hd1b[(t+1)&1]; x.out2=nullptr; return x; };
    auto OW = [&](int t){ Slice x{}; x.mode=1;
        x.A0=hd1b[(t+1)&1]; x.K0=t; x.Wlo=owb; x.bp=o_b; x.hout=out; return x; };
    Slice NS{}; NS.mode = -1;

    // ---- conductor: C_init + 16 combined steps ----
    hipLaunchKernelGGL((fused_step<32>), dim3(HB, BBc/32, 1), dim3(256),0,stream, CL0(0), NS, NS);
    for (int s=0;s<NEc;s++){
        if (s < NEc-1)
            hipLaunchKernelGGL((fused_step<32>), dim3(HB, BBc/32, 2), dim3(256),0,stream,
                               CL1(s), CL0(s+1), NS);
        else
            hipLaunchKernelGGL((fused_step<32>), dim3(HB, BBc/32, 1), dim3(256),0,stream,
                               CL1(s), NS, NS);
    }

    // ---- embedding: emb = tanh(cout @ ce_w^T + b) -> bf16 ----
    hipLaunchKernelGGL((gemm_bf<64,128>), dim3(LLc/128, NEBc/64), dim3(256),0,stream,
                       coutb, cewb, emb, HHc, LLc);
    hipLaunchKernelGGL(bias_tanh4, dim3((NEBc*LLc/4)/256), dim3(256),0,stream, emb, ce_b, embb);

    // ---- decoder: D_init + 16 combined steps (BM=128) + final softmax ----
    hipLaunchKernelGGL((fused_step<128>), dim3(HB, NEBc/128, 1), dim3(256),0,stream, DL0(0), NS, NS);
    for (int t=0;t<SSc;t++){
        Slice s1 = (t < SSc-1) ? DL0(t+1) : NS;
        Slice s2 = (t >= 1) ? OW(t-1) : NS;
        const int nz = (t >= 1) ? 3 : 2;
        hipLaunchKernelGGL((fused_step<128>), dim3(HB, NEBc/128, nz), dim3(256),0,stream,
                           DL1(t), s1, s2);
    }
    hipLaunchKernelGGL((fused_step<64>), dim3(1, NEBc/64, 1), dim3(256),0,stream, OW(SSc-1), NS, NS);
}

// Round 10
// 2860.246 us; speedup vs baseline: 1.4082x; 1.4030x over previous
//
#include <hip/hip_runtime.h>
#include <hip/hip_bf16.h>
#include <cstdint>
#include <cstddef>

#define NEc 16
#define SSc 16
#define BBc 256
#define INc 61
#define HHc 1024
#define LLc 512
#define H3c 3072
#define NEBc 4096   // NE*B
#define KXc 64      // x width padded 61->64
#define HB  16      // h-blocks of 64

typedef __hip_bfloat16 bf16;
typedef __attribute__((ext_vector_type(8))) short bf16x8;   // 8 bf16 = 4 VGPR (MFMA A/B frag)
typedef __attribute__((ext_vector_type(4))) float f32x4;    // MFMA C/D frag
typedef __attribute__((ext_vector_type(4))) short s16x4;    // 4 bf16 packed store

__device__ __forceinline__ void gload16(const void* g, void* l){
    __builtin_amdgcn_global_load_lds((const __attribute__((address_space(1))) unsigned int*)g,
                                     (__attribute__((address_space(3))) unsigned int*)l, 16, 0, 0);
}

__device__ __forceinline__ float sigmoidf_(float x){ return 1.0f/(1.0f+__expf(-x)); }

// One work-slice for the multi-role fused kernel.
// mode: -1 = inactive, 0 = fused GRU cell, 1 = output-projection+softmax.
// GRU: pre-act = A0@Wlo[0:K0] + A1@Wlo[K0:K0+K1] + A2@Whi (r,z always; 'in'
// from the lo phases, 'hn' from the hi phase), then full gate math in-register.
// ALL buffers per dispatch are read-only or write-only (fp32 h double-buffered).
// OWSM: A0 = h bf16, Wlo = o_w padded [64][1024], bp = o_b, hout = out, K0 = t.
struct Slice {
    const bf16* A0; int lda0; int K0;
    const bf16* A1; int lda1; int K1;
    const bf16* A2; int lda2;
    const bf16* Wlo;
    const bf16* Whi;
    const float* bp;
    const float* hin;
    float* hout;
    bf16* hbout;
    bf16* out2;
    int mode;
};

// One staged k-step: stage A-tile (BM rows x 128B) + B-tile (192 rows x 128B),
// then 2 ks-halves x {r,z,NIDX} MFMAs. NIDX=2 (lo: 'in') or 3 (hi: 'hn').
#define GRU_KSTEP(APTR, ALDA, ACOL, BPTR, BLDB, BCOL, NIDX)                              \
  {                                                                                      \
    if (!first) __syncthreads();                                                         \
    first = false;                                                                       \
    _Pragma("unroll")                                                                    \
    for (int i=0;i<MR;i++){                                                              \
        const int o = i*4096 + tid*16;                                                   \
        const int u = o ^ (((o>>7)&7)<<4);                                               \
        gload16((APTR) + (size_t)(m0 + (u>>7))*(ALDA) + (ACOL) + ((u&127)>>1), sA + o);  \
    }                                                                                    \
    _Pragma("unroll")                                                                    \
    for (int i=0;i<6;i++){                                                               \
        const int o = i*4096 + tid*16;                                                   \
        const int u = o ^ (((o>>7)&7)<<4);                                               \
        gload16((BPTR) + (size_t)(u>>7)*(BLDB) + (BCOL) + ((u&127)>>1), sB + o);         \
    }                                                                                    \
    __syncthreads();                                                                     \
    _Pragma("unroll")                                                                    \
    for (int ks=0;ks<2;ks++){                                                            \
        bf16x8 av[MR];                                                                   \
        _Pragma("unroll")                                                                \
        for (int mi=0;mi<MR;mi++){                                                       \
            const int r = wm*(BM/2) + mi*16 + lr;                                        \
            const int u = r*128 + ks*64 + lk*16;                                         \
            av[mi] = *(const bf16x8*)(sA + (u ^ ((r&7)<<4)));                            \
        }                                                                                \
        _Pragma("unroll")                                                                \
        for (int hs=0;hs<2;hs++){                                                        \
            _Pragma("unroll")                                                            \
            for (int g3=0;g3<3;g3++){                                                    \
                const int br = ((wc*2+hs)*3 + g3)*16 + lr;                               \
                const int u  = br*128 + ks*64 + lk*16;                                   \
                const bf16x8 bv = *(const bf16x8*)(sB + (u ^ ((br&7)<<4)));              \
                const int gi_ = (g3<2) ? g3 : (NIDX);                                    \
                _Pragma("unroll")                                                        \
                for (int mi=0;mi<MR;mi++)                                                \
                    acc[mi][hs][gi_] = __builtin_amdgcn_mfma_f32_16x16x32_bf16(          \
                        av[mi], bv, acc[mi][hs][gi_], 0,0,0);                            \
            }                                                                            \
        }                                                                                \
    }                                                                                    \
  }

// ---------------------------------------------------------------------------
// Fused GRU body. Packed weight layout per hb (64 h-cols): 192 B-rows,
// row c: g=c>>4, hsub=g/3, gate=g%3 (r,z,n), h-col = hb*64+hsub*16+(c&15).
// Wave (wm,wc): wm = row half, wc = hsub pair. Each lane holds r,z,in,hn of
// one h element -> pure-register epilogue. Three dedicated k-loops (A0,A1,A2).
// BM=64 (MR=2): LDS exactly 32768 -> 5 blocks/CU; VGPR ~80 -> high residency
// (the binding constraint per R8/R9: residency, not LDS-read ratio).
// ---------------------------------------------------------------------------
template<int BM>
__device__ void gru_body(const Slice& s, char* smem)
{
    constexpr int MR = BM/32;
    char* sA = smem;
    char* sB = smem + BM*128;

    const int tid  = threadIdx.x;
    const int lane = tid & 63;
    const int wave = tid >> 6;
    const int wm   = wave >> 1;
    const int wc   = wave & 1;
    const int lr   = lane & 15;
    const int lk   = lane >> 4;
    const int hb   = blockIdx.x;
    const int m0   = blockIdx.y * BM;

    const int Klo = s.K0 + s.K1;
    const bf16* WloB = s.Wlo + (size_t)hb*192*Klo;
    const bf16* WhiB = s.Whi + (size_t)hb*192*1024;

    f32x4 acc[MR][2][4];                        // [mi][hsub-local][r,z,in,hn]
    #pragma unroll
    for (int mi=0;mi<MR;mi++)
      #pragma unroll
      for (int hs=0;hs<2;hs++)
        #pragma unroll
        for (int g=0;g<4;g++)
          #pragma unroll
          for (int j=0;j<4;j++) acc[mi][hs][g][j] = 0.f;

    bool first = true;

    {   // ---- loop A: A0 x Wlo[0:K0] -> r,z,'in' ----
        const bf16* Ap = s.A0; const int Al = s.lda0; const int Kp = s.K0;
        for (int k0 = 0; k0 < Kp; k0 += 64) GRU_KSTEP(Ap, Al, k0, WloB, Klo, k0, 2)
    }
    if (s.K1 > 0){  // ---- loop B: A1 x Wlo[K0:K0+K1] -> r,z,'in' ----
        const bf16* Ap = s.A1; const int Al = s.lda1; const int Kp = s.K1; const int c0 = s.K0;
        for (int k0 = 0; k0 < Kp; k0 += 64) GRU_KSTEP(Ap, Al, k0, WloB, Klo, c0 + k0, 2)
    }
    {   // ---- loop C: A2 x Whi (K=1024) -> r,z,'hn' ----
        const bf16* Ap = s.A2; const int Al = s.lda2;
        for (int k0 = 0; k0 < 1024; k0 += 64) GRU_KSTEP(Ap, Al, k0, WhiB, 1024, k0, 3)
    }

    // ---- pure-register epilogue (hin read-only, hout write-only) ----
    #pragma unroll
    for (int hs=0;hs<2;hs++){
        const int hsub = wc*2 + hs;
        const int hc   = hb*64 + hsub*16 + lr;
        const float bpr  = s.bp[hb*256 +       hsub*16 + lr];
        const float bpz  = s.bp[hb*256 +  64 + hsub*16 + lr];
        const float bpin = s.bp[hb*256 + 128 + hsub*16 + lr];
        const float bphn = s.bp[hb*256 + 192 + hsub*16 + lr];
        #pragma unroll
        for (int mi=0;mi<MR;mi++)
          #pragma unroll
          for (int j=0;j<4;j++){
            const int rl = wm*(BM/2) + mi*16 + lk*4 + j;   // C/D: row=(lane>>4)*4+j
            const int m  = m0 + rl;
            const float r = sigmoidf_(acc[mi][hs][0][j] + bpr);
            const float z = sigmoidf_(acc[mi][hs][1][j] + bpz);
            const float n = tanhf(acc[mi][hs][2][j] + bpin + r*(acc[mi][hs][3][j] + bphn));
            const size_t off = (size_t)m*HHc + hc;
            const float hnew = (1.f - z)*n + z*s.hin[off];
            s.hout[off] = hnew;
            const bf16 hb16 = __float2bfloat16(hnew);
            s.hbout[off] = hb16;
            if (s.out2) s.out2[off] = hb16;
          }
    }
}

// ---------------------------------------------------------------------------
// Output projection + softmax body (64-row tile; active iff blockIdx.x==0,
// tile = blockIdx.y). lg overlaps sA/sB (17408B <= 32768) - reused after a
// barrier so the fused kernel's LDS stays exactly 32KB (5 blocks/CU).
// logits = A0 @ Wlo(o_w padded)^T + bp(o_b); softmax over 61; scatter to hout.
// ---------------------------------------------------------------------------
__device__ void owsm_body(const Slice& s, char* smem)
{
    if (blockIdx.x != 0) return;
    char* sA = smem; char* sB = smem + 8192;
    const int tid  = threadIdx.x;
    const int lane = tid & 63;
    const int wave = tid >> 6;
    const int wm   = wave >> 1;
    const int wc   = wave & 1;
    const int lr   = lane & 15;
    const int lk   = lane >> 4;
    const int m0   = blockIdx.y * 64;
    const int t    = s.K0;

    f32x4 acc[2][2];
    #pragma unroll
    for (int mi=0;mi<2;mi++)
      #pragma unroll
      for (int ni=0;ni<2;ni++)
        #pragma unroll
        for (int j=0;j<4;j++) acc[mi][ni][j]=0.f;

    for (int k0=0;k0<1024;k0+=64){
        if (k0) __syncthreads();
        #pragma unroll
        for (int i=0;i<2;i++){
            const int o = i*4096 + tid*16;
            const int u = o ^ (((o>>7)&7)<<4);
            gload16(s.A0 + (size_t)(m0 + (u>>7))*1024 + k0 + ((u&127)>>1), sA + o);
        }
        #pragma unroll
        for (int i=0;i<2;i++){
            const int o = i*4096 + tid*16;
            const int u = o ^ (((o>>7)&7)<<4);
            gload16(s.Wlo + (size_t)(u>>7)*1024 + k0 + ((u&127)>>1), sB + o);
        }
        __syncthreads();
        #pragma unroll
        for (int ks=0;ks<2;ks++){
            bf16x8 av[2], bv[2];
            #pragma unroll
            for (int mi=0;mi<2;mi++){
                const int r = wm*32 + mi*16 + lr;
                const int u = r*128 + ks*64 + lk*16;
                av[mi] = *(const bf16x8*)(sA + (u ^ ((r&7)<<4)));
            }
            #pragma unroll
            for (int ni=0;ni<2;ni++){
                const int r = wc*32 + ni*16 + lr;
                const int u = r*128 + ks*64 + lk*16;
                bv[ni] = *(const bf16x8*)(sB + (u ^ ((r&7)<<4)));
            }
            #pragma unroll
            for (int mi=0;mi<2;mi++)
              #pragma unroll
              for (int ni=0;ni<2;ni++)
                acc[mi][ni] = __builtin_amdgcn_mfma_f32_16x16x32_bf16(av[mi], bv[ni], acc[mi][ni], 0,0,0);
        }
    }
    __syncthreads();                           // all sA/sB reads done; reuse as lg
    float* lg = (float*)smem;                  // [64][68] = 17408 B
    #pragma unroll
    for (int mi=0;mi<2;mi++)
      #pragma unroll
      for (int ni=0;ni<2;ni++)
        #pragma unroll
        for (int j=0;j<4;j++){
            const int rl = wm*32 + mi*16 + lk*4 + j;
            const int c  = wc*32 + ni*16 + lr;
            lg[rl*68 + c] = (c < INc) ? (acc[mi][ni][j] + s.bp[c]) : -1e30f;
        }
    __syncthreads();
    const int row = tid >> 2;
    const int q   = tid & 3;
    float mx = -1e30f;
    #pragma unroll
    for (int i=0;i<16;i++) mx = fmaxf(mx, lg[row*68 + q*16+i]);
    mx = fmaxf(mx, __shfl_xor(mx,1));
    mx = fmaxf(mx, __shfl_xor(mx,2));
    float ev[16];
    float sum = 0.f;
    #pragma unroll
    for (int i=0;i<16;i++){ ev[i] = __expf(lg[row*68 + q*16+i] - mx); sum += ev[i]; }
    sum += __shfl_xor(sum,1);
    sum += __shfl_xor(sum,2);
    const float inv = 1.f/sum;
    const int R = m0 + row;
    const int ne = R >> 8, b = R & 255;
    float* op = s.hout + ((size_t)((ne*SSc + t)*BBc + b))*INc;
    #pragma unroll
    for (int i=0;i<16;i++){
        const int c = q*16 + i;
        if (c < INc) op[c] = ev[i]*inv;
    }
}

// ---------------------------------------------------------------------------
// Multi-role fused step kernel: one independent Slice per blockIdx.z.
// LDS = (BM+192)*128 exactly (32768 at BM=64 -> 5 blocks/CU).
// ---------------------------------------------------------------------------
template<int BM>
__global__ __launch_bounds__(256)
void fused_step(Slice s0, Slice s1, Slice s2)
{
    __shared__ char smem[(BM+192)*128];
    const Slice& s = (blockIdx.z==0) ? s0 : (blockIdx.z==1) ? s1 : s2;
    if (s.mode < 0) return;
    if constexpr (BM>=64){
        if (s.mode == 1){ owsm_body(s, smem); return; }
    }
    gru_body<BM>(s, smem);
}

// ---------------------------------------------------------------------------
// plain bf16 GEMM-NT (proven): C[M,N] = A[M,K] @ B[N,K]^T, C fp32 (embedding)
// ---------------------------------------------------------------------------
template<int BM,int BN>
__global__ __launch_bounds__(256)
void gemm_bf(const bf16* __restrict__ A, const bf16* __restrict__ Bm, float* __restrict__ C,
             int K, int ldc)
{
    constexpr int WAVES_M = (BM==128) ? 2 : 1;
    constexpr int WM = BM / WAVES_M;
    constexpr int WN = BN / (4/WAVES_M);
    constexpr int MR = WM / 16;
    constexpr int NR = WN / 16;
    constexpr int ASW = (BM*128)/4096;
    constexpr int BSW = (BN*128)/4096;

    __shared__ char smem[(BM+BN)*128];
    char* sA = smem;
    char* sB = smem + BM*128;

    const int tid  = threadIdx.x;
    const int lane = tid & 63;
    const int wave = tid >> 6;
    const int wm   = (WAVES_M==2) ? (wave>>1) : 0;
    const int wn   = (WAVES_M==2) ? (wave&1)  : wave;
    const int lr   = lane & 15;
    const int lk   = lane >> 4;
    const int m0   = blockIdx.y * BM;
    const int n0   = blockIdx.x * BN;

    f32x4 acc[MR][NR];
    #pragma unroll
    for (int mi=0;mi<MR;mi++)
      #pragma unroll
      for (int ni=0;ni<NR;ni++)
        #pragma unroll
        for (int j=0;j<4;j++) acc[mi][ni][j] = 0.f;

    for (int k0 = 0; k0 < K; k0 += 64){
        if (k0) __syncthreads();
        #pragma unroll
        for (int i=0;i<ASW;i++){
            const int o = i*4096 + tid*16;
            const int u = o ^ (((o>>7)&7)<<4);
            gload16(A + (size_t)(m0 + (u>>7))*K + k0 + ((u&127)>>1), sA + o);
        }
        #pragma unroll
        for (int i=0;i<BSW;i++){
            const int o = i*4096 + tid*16;
            const int u = o ^ (((o>>7)&7)<<4);
            gload16(Bm + (size_t)(n0 + (u>>7))*K + k0 + ((u&127)>>1), sB + o);
        }
        __syncthreads();
        #pragma unroll
        for (int ks=0;ks<2;ks++){
            bf16x8 av[MR], bv[NR];
            #pragma unroll
            for (int mi=0;mi<MR;mi++){
                const int r = wm*WM + mi*16 + lr;
                const int u = r*128 + ks*64 + lk*16;
                av[mi] = *(const bf16x8*)(sA + (u ^ ((r&7)<<4)));
            }
            #pragma unroll
            for (int ni=0;ni<NR;ni++){
                const int r = wn*WN + ni*16 + lr;
                const int u = r*128 + ks*64 + lk*16;
                bv[ni] = *(const bf16x8*)(sB + (u ^ ((r&7)<<4)));
            }
            #pragma unroll
            for (int mi=0;mi<MR;mi++)
              #pragma unroll
              for (int ni=0;ni<NR;ni++)
                acc[mi][ni] = __builtin_amdgcn_mfma_f32_16x16x32_bf16(av[mi], bv[ni], acc[mi][ni], 0,0,0);
        }
    }
    #pragma unroll
    for (int mi=0;mi<MR;mi++)
      #pragma unroll
      for (int ni=0;ni<NR;ni++)
        #pragma unroll
        for (int j=0;j<4;j++){
            const int r = m0 + wm*WM + mi*16 + lk*4 + j;
            const int c = n0 + wn*WN + ni*16 + lr;
            C[(size_t)r*ldc + c] = acc[mi][ni][j];
        }
}

// ---------------------------------------------------------------------------
// setup kernels
// ---------------------------------------------------------------------------
__global__ __launch_bounds__(256) void pack_w2(const float* __restrict__ src, int srcld,
                                               int col0, int Kvalid, int Kchunk,
                                               bf16* __restrict__ dst, int dstld, int dstc0,
                                               int total){
    const int idx = blockIdx.x*256 + threadIdx.x;
    if (idx >= total) return;
    const int k  = idx % Kchunk;
    const int c  = (idx / Kchunk) % 192;
    const int hb = idx / (Kchunk*192);
    const int g  = c >> 4;
    const int hsub = g/3;
    const int gate = g - hsub*3;
    const int row = gate*HHc + hb*64 + hsub*16 + (c & 15);
    const float v = (k < Kvalid) ? src[(size_t)row*srcld + col0 + k] : 0.f;
    dst[((size_t)hb*192 + c)*dstld + dstc0 + k] = __float2bfloat16(v);
}

// bp[hb][256] = [bih_r+bhh_r][bih_z+bhh_z][bih_n][bhh_n], within-64 = h offset
__global__ __launch_bounds__(256) void pack_bias(const float* __restrict__ bih,
                                                 const float* __restrict__ bhh,
                                                 float* __restrict__ bp){
    const int idx = blockIdx.x*256 + threadIdx.x;
    if (idx >= HB*256) return;
    const int c  = idx & 255;
    const int hb = idx >> 8;
    const int i  = hb*64 + (c&63);
    const int g  = c >> 6;
    float v;
    if      (g==0) v = bih[i] + bhh[i];
    else if (g==1) v = bih[HHc+i] + bhh[HHc+i];
    else if (g==2) v = bih[2*HHc+i];
    else           v = bhh[2*HHc+i];
    bp[idx] = v;
}

__global__ __launch_bounds__(256) void cvt_bf16_k(const float* __restrict__ in, bf16* __restrict__ out, int n4){
    const int i = blockIdx.x*256 + threadIdx.x;
    if (i >= n4) return;
    const f32x4 v = *(const f32x4*)(in + (size_t)i*4);
    union { s16x4 s; bf16 b[4]; } u;
    #pragma unroll
    for (int j=0;j<4;j++) u.b[j] = __float2bfloat16(v[j]);
    *(s16x4*)(out + (size_t)i*4) = u.s;
}

// o_w [61][1024] -> owb [64][1024] zero-padded rows
__global__ __launch_bounds__(256) void pad_ow(const float* __restrict__ w, bf16* __restrict__ o){
    const int idx = blockIdx.x*256 + threadIdx.x;
    if (idx >= KXc*HHc) return;
    const int r = idx >> 10;
    o[idx] = __float2bfloat16(r < INc ? w[(size_t)r*HHc + (idx & (HHc-1))] : 0.f);
}

// target [NE*S][B][61] -> xb bf16 [S][NE*B][64] zero-padded
__global__ __launch_bounds__(256) void build_xb(const float* __restrict__ t, bf16* __restrict__ xb){
    const int idx = blockIdx.x*256 + threadIdx.x;
    if (idx >= SSc*NEBc*KXc) return;
    const int c  = idx & 63;
    const int rr = idx >> 6;
    const int s  = rr >> 12;
    const int r  = rr & 4095;
    const int ne = r >> 8;
    const int b  = r & 255;
    const float v = (c < INc) ? t[(((size_t)(ne*SSc + s)*BBc + b)*INc) + c] : 0.f;
    xb[idx] = __float2bfloat16(v);
}

// h0 [2][256][1024] -> h0cf/h1cf fp32 + bf16 shadows
__global__ __launch_bounds__(256) void init_hc(const float* __restrict__ h0,
                                               float* __restrict__ h0c, float* __restrict__ h1c,
                                               bf16* __restrict__ h0cb, bf16* __restrict__ h1cb){
    const int i = blockIdx.x*256 + threadIdx.x;
    if (i >= (BBc*HHc)/4) return;
    const int e = i*4;
    f32x4 a = *(const f32x4*)(h0 + e);
    f32x4 b = *(const f32x4*)(h0 + BBc*HHc + e);
    union { s16x4 v; bf16 q[4]; } ua, ub;
    #pragma unroll
    for (int j=0;j<4;j++){ ua.q[j]=__float2bfloat16(a[j]); ub.q[j]=__float2bfloat16(b[j]); }
    *(f32x4*)(h0c + e) = a; *(f32x4*)(h1c + e) = b;
    *(s16x4*)(h0cb + e) = ua.v; *(s16x4*)(h1cb + e) = ub.v;
}

// h0_dec [NE][2][256][1024] -> hd0f/hd1f [NE*B][H] fp32 + bf16
__global__ __launch_bounds__(256) void init_hd(const float* __restrict__ hd,
                                               float* __restrict__ hd0, float* __restrict__ hd1,
                                               bf16* __restrict__ hd0b, bf16* __restrict__ hd1b){
    const int i = blockIdx.x*256 + threadIdx.x;
    if (i >= (NEBc*HHc)/4) return;
    const int e  = i*4;
    const int hh = e & (HHc-1);
    const int r  = e >> 10;
    const int ne = r >> 8;
    const int b  = r & 255;
    f32x4 a = *(const f32x4*)(hd + (((size_t)ne*2 + 0)*BBc + b)*HHc + hh);
    f32x4 c = *(const f32x4*)(hd + (((size_t)ne*2 + 1)*BBc + b)*HHc + hh);
    union { s16x4 v; bf16 q[4]; } ua, uc;
    #pragma unroll
    for (int j=0;j<4;j++){ ua.q[j]=__float2bfloat16(a[j]); uc.q[j]=__float2bfloat16(c[j]); }
    *(f32x4*)(hd0 + e) = a; *(f32x4*)(hd1 + e) = c;
    *(s16x4*)(hd0b + e) = ua.v; *(s16x4*)(hd1b + e) = uc.v;
}

__global__ __launch_bounds__(256) void bias_tanh4(const float* __restrict__ in,
                                                  const float* __restrict__ b, bf16* __restrict__ out){
    const int i = blockIdx.x*256 + threadIdx.x;
    if (i >= (NEBc*LLc)/4) return;
    const int e = i*4;
    const int c = e & (LLc-1);
    f32x4 v = *(const f32x4*)(in + e);
    f32x4 bb = *(const f32x4*)(b + c);
    union { s16x4 s; bf16 q[4]; } u;
    #pragma unroll
    for (int j=0;j<4;j++) u.q[j] = __float2bfloat16(tanhf(v[j] + bb[j]));
    *(s16x4*)(out + e) = u.s;
}

// ---------------- host side ----------------

extern "C" void kernel_launch(void* const* d_in, const int* in_sizes, int n_in,
                              void* d_out, int out_size, void* d_ws, size_t ws_size,
                              hipStream_t stream)
{
    const float* target = (const float*)d_in[0];
    const float* latent = (const float*)d_in[1];
    const float* h0     = (const float*)d_in[2];
    const float* h0_dec = (const float*)d_in[3];
    const float* c_wih0 = (const float*)d_in[4];
    const float* c_whh0 = (const float*)d_in[5];
    const float* c_bih0 = (const float*)d_in[6];
    const float* c_bhh0 = (const float*)d_in[7];
    const float* c_wih1 = (const float*)d_in[8];
    const float* c_whh1 = (const float*)d_in[9];
    const float* c_bih1 = (const float*)d_in[10];
    const float* c_bhh1 = (const float*)d_in[11];
    const float* ce_w   = (const float*)d_in[12];
    const float* ce_b   = (const float*)d_in[13];
    const float* d_wih0 = (const float*)d_in[14];
    const float* d_whh0 = (const float*)d_in[15];
    const float* d_bih0 = (const float*)d_in[16];
    const float* d_bhh0 = (const float*)d_in[17];
    const float* d_wih1 = (const float*)d_in[18];
    const float* d_whh1 = (const float*)d_in[19];
    const float* d_bih1 = (const float*)d_in[20];
    const float* d_bhh1 = (const float*)d_in[21];
    const float* o_w    = (const float*)d_in[22];
    const float* o_b    = (const float*)d_in[23];
    float* out = (float*)d_out;

    // ---- workspace (fp32 h fully double-buffered: no RMW anywhere) ----
    float* fp = (float*)d_ws;
    auto fa = [&](size_t n){ float* q = fp; fp += n; return q; };
    float* hd0f[2] = { fa((size_t)NEBc*HHc), fa((size_t)NEBc*HHc) };
    float* hd1f[2] = { fa((size_t)NEBc*HHc), fa((size_t)NEBc*HHc) };
    float* h0cf[2] = { fa((size_t)BBc*HHc),  fa((size_t)BBc*HHc) };
    float* h1cf[2] = { fa((size_t)BBc*HHc),  fa((size_t)BBc*HHc) };
    float* emb   = fa((size_t)NEBc*LLc);
    float* bp_c0 = fa(HB*256);
    float* bp_c1 = fa(HB*256);
    float* bp_d0 = fa(HB*256);
    float* bp_d1 = fa(HB*256);

    bf16* bbp = (bf16*)fp;
    auto ba = [&](size_t n){ bf16* q = bbp; bbp += n; return q; };
    bf16* hd0b[2] = { ba((size_t)NEBc*HHc), ba((size_t)NEBc*HHc) };
    bf16* hd1b[2] = { ba((size_t)NEBc*HHc), ba((size_t)NEBc*HHc) };
    bf16* h0cb[2] = { ba((size_t)BBc*HHc),  ba((size_t)BBc*HHc) };
    bf16* h1cb[2] = { ba((size_t)BBc*HHc),  ba((size_t)BBc*HHc) };
    bf16* xb     = ba((size_t)SSc*NEBc*KXc);
    bf16* coutb  = ba((size_t)NEBc*HHc);
    bf16* embb   = ba((size_t)NEBc*LLc);
    bf16* latb   = ba((size_t)BBc*LLc);
    bf16* Wloc0  = ba((size_t)HB*192*LLc);      // conductor l0: latent phase (K=512)
    bf16* Whic0  = ba((size_t)HB*192*HHc);
    bf16* Wloc1  = ba((size_t)HB*192*HHc);
    bf16* Whic1  = ba((size_t)HB*192*HHc);
    bf16* Wlod0f = ba((size_t)HB*192*576);      // decoder l0: [x(64) | emb(512)]
    bf16* Whid0  = ba((size_t)HB*192*HHc);
    bf16* Wlod1  = ba((size_t)HB*192*HHc);
    bf16* Whid1  = ba((size_t)HB*192*HHc);
    bf16* cewb   = ba((size_t)LLc*HHc);
    bf16* owb    = ba((size_t)KXc*HHc);

    auto packw = [&](const float* src, int srcld, int col0, int kv, int kchunk,
                     bf16* dst, int dstld, int dstc0){
        const int tot = HB*192*kchunk;
        hipLaunchKernelGGL(pack_w2, dim3((tot+255)/256), dim3(256),0,stream,
                           src,srcld,col0,kv,kchunk,dst,dstld,dstc0,tot);
    };

    // ---- setup ----
    hipLaunchKernelGGL(cvt_bf16_k, dim3((BBc*LLc/4+255)/256), dim3(256),0,stream, latent, latb, BBc*LLc/4);
    hipLaunchKernelGGL(cvt_bf16_k, dim3((LLc*HHc/4+255)/256), dim3(256),0,stream, ce_w, cewb, LLc*HHc/4);
    hipLaunchKernelGGL(pad_ow, dim3((KXc*HHc)/256), dim3(256),0,stream, o_w, owb);
    hipLaunchKernelGGL(build_xb, dim3((SSc*NEBc*KXc)/256), dim3(256),0,stream, target, xb);
    hipLaunchKernelGGL(init_hc, dim3((BBc*HHc/4)/256), dim3(256),0,stream, h0, h0cf[0], h1cf[0], h0cb[0], h1cb[0]);
    hipLaunchKernelGGL(init_hd, dim3((NEBc*HHc/4)/256), dim3(256),0,stream, h0_dec, hd0f[0], hd1f[0], hd0b[0], hd1b[0]);
    packw(c_wih0, LLc,     0,   LLc, LLc,  Wloc0, LLc, 0);
    packw(c_whh0, HHc,     0,   HHc, HHc,  Whic0, HHc, 0);
    packw(c_wih1, HHc,     0,   HHc, HHc,  Wloc1, HHc, 0);
    packw(c_whh1, HHc,     0,   HHc, HHc,  Whic1, HHc, 0);
    packw(d_wih0, INc+LLc, 0,   INc, KXc,  Wlod0f, 576, 0);
    packw(d_wih0, INc+LLc, INc, LLc, LLc,  Wlod0f, 576, KXc);
    packw(d_whh0, HHc,     0,   HHc, HHc,  Whid0, HHc, 0);
    packw(d_wih1, HHc,     0,   HHc, HHc,  Wlod1, HHc, 0);
    packw(d_whh1, HHc,     0,   HHc, HHc,  Whid1, HHc, 0);
    hipLaunchKernelGGL(pack_bias, dim3((HB*256+255)/256), dim3(256),0,stream, c_bih0, c_bhh0, bp_c0);
    hipLaunchKernelGGL(pack_bias, dim3((HB*256+255)/256), dim3(256),0,stream, c_bih1, c_bhh1, bp_c1);
    hipLaunchKernelGGL(pack_bias, dim3((HB*256+255)/256), dim3(256),0,stream, d_bih0, d_bhh0, bp_d0);
    hipLaunchKernelGGL(pack_bias, dim3((HB*256+255)/256), dim3(256),0,stream, d_bih1, d_bhh1, bp_d1);

    // ---- slice builders (host) ----
    auto CL0 = [&](int s){ Slice x{}; x.mode=0;
        x.A0=latb; x.lda0=LLc; x.K0=LLc; x.A1=nullptr; x.lda1=0; x.K1=0;
        x.A2=h0cb[s&1]; x.lda2=HHc; x.Wlo=Wloc0; x.Whi=Whic0; x.bp=bp_c0;
        x.hin=h0cf[s&1]; x.hout=h0cf[(s+1)&1]; x.hbout=h0cb[(s+1)&1]; x.out2=nullptr; return x; };
    auto CL1 = [&](int s){ Slice x{}; x.mode=0;
        x.A0=h0cb[(s+1)&1]; x.lda0=HHc; x.K0=HHc; x.A1=nullptr; x.lda1=0; x.K1=0;
        x.A2=h1cb[s&1]; x.lda2=HHc; x.Wlo=Wloc1; x.Whi=Whic1; x.bp=bp_c1;
        x.hin=h1cf[s&1]; x.hout=h1cf[(s+1)&1]; x.hbout=h1cb[(s+1)&1];
        x.out2=coutb + (size_t)s*BBc*HHc; return x; };
    auto DL0 = [&](int t){ Slice x{}; x.mode=0;
        x.A0=xb + (size_t)t*NEBc*KXc; x.lda0=KXc; x.K0=KXc;
        x.A1=embb; x.lda1=LLc; x.K1=LLc;
        x.A2=hd0b[t&1]; x.lda2=HHc; x.Wlo=Wlod0f; x.Whi=Whid0; x.bp=bp_d0;
        x.hin=hd0f[t&1]; x.hout=hd0f[(t+1)&1]; x.hbout=hd0b[(t+1)&1]; x.out2=nullptr; return x; };
    auto DL1 = [&](int t){ Slice x{}; x.mode=0;
        x.A0=hd0b[(t+1)&1]; x.lda0=HHc; x.K0=HHc; x.A1=nullptr; x.lda1=0; x.K1=0;
        x.A2=hd1b[t&1]; x.lda2=HHc; x.Wlo=Wlod1; x.Whi=Whid1; x.bp=bp_d1;
        x.hin=hd1f[t&1]; x.hout=hd1f[(t+1)&1]; x.hbout=hd1b[(t+1)&1]; x.out2=nullptr; return x; };
    auto OW = [&](int t){ Slice x{}; x.mode=1;
        x.A0=hd1b[(t+1)&1]; x.K0=t; x.Wlo=owb; x.bp=o_b; x.hout=out; return x; };
    Slice NS{}; NS.mode = -1;

    // ---- conductor: C_init + 16 combined steps (BM=32) ----
    hipLaunchKernelGGL((fused_step<32>), dim3(HB, BBc/32, 1), dim3(256),0,stream, CL0(0), NS, NS);
    for (int s=0;s<NEc;s++){
        if (s < NEc-1)
            hipLaunchKernelGGL((fused_step<32>), dim3(HB, BBc/32, 2), dim3(256),0,stream,
                               CL1(s), CL0(s+1), NS);
        else
            hipLaunchKernelGGL((fused_step<32>), dim3(HB, BBc/32, 1), dim3(256),0,stream,
                               CL1(s), NS, NS);
    }

    // ---- embedding: emb = tanh(cout @ ce_w^T + b) -> bf16 ----
    hipLaunchKernelGGL((gemm_bf<64,128>), dim3(LLc/128, NEBc/64), dim3(256),0,stream,
                       coutb, cewb, emb, HHc, LLc);
    hipLaunchKernelGGL(bias_tanh4, dim3((NEBc*LLc/4)/256), dim3(256),0,stream, emb, ce_b, embb);

    // ---- decoder: D_init + 16 combined steps (BM=64, 5 blocks/CU) ----
    hipLaunchKernelGGL((fused_step<64>), dim3(HB, NEBc/64, 1), dim3(256),0,stream, DL0(0), NS, NS);
    for (int t=0;t<SSc;t++){
        Slice s1 = (t < SSc-1) ? DL0(t+1) : NS;
        Slice s2 = (t >= 1) ? OW(t-1) : NS;
        const int nz = (t >= 1) ? 3 : 2;
        hipLaunchKernelGGL((fused_step<64>), dim3(HB, NEBc/64, nz), dim3(256),0,stream,
                           DL1(t), s1, s2);
    }
    hipLaunchKernelGGL((fused_step<64>), dim3(1, NEBc/64, 1), dim3(256),0,stream, OW(SSc-1), NS, NS);
}